// Round 3
// baseline (1628.561 us; speedup 1.0000x reference)
//
#include <hip/hip_runtime.h>
#include <hip/hip_bf16.h>

typedef unsigned short u16;

#define NNODES 100000
#define NEDGES 600000
#define NGRAPHS 512
#define HF 128
#define EF 256

__device__ __forceinline__ float bfu(u16 u){ return __uint_as_float(((unsigned)u) << 16); }
__device__ __forceinline__ float sp_f(float x){ return fmaxf(x, 0.f) + log1pf(expf(-fabsf(x))); }
__device__ __forceinline__ float sig_f(float x){ return 1.f / (1.f + expf(-x)); }
__device__ __forceinline__ u16 f2bf(float f){
    unsigned u = __float_as_uint(f);
    unsigned r = (u + 0x7fff + ((u >> 16) & 1)) >> 16;
    return (u16)r;
}

// storage-type helpers for ws-resident x/M (fp32 compute everywhere)
__device__ __forceinline__ float ld1(const float* p){ return *p; }
__device__ __forceinline__ float ld1(const u16* p){ return bfu(*p); }
__device__ __forceinline__ void st1(float* p, float v){ *p = v; }
__device__ __forceinline__ void st1(u16* p, float v){ *p = f2bf(v); }

// ---------------- input dtype detection ----------------
// Interpret first 256 u16 of the embed table as bf16. True-bf16 storage of
// N(0,0.05) weights never exceeds 1.0; fp32 storage yields ~50% of the
// low-mantissa halves with |bf16| > 1. flag=1 -> fp32 storage.
__global__ __launch_bounds__(256) void detect_kernel(const u16* __restrict__ probe,
                                                     int* __restrict__ flag){
    __shared__ int s[256];
    int t = threadIdx.x;
    float v = bfu(probe[t]);
    s[t] = (fabsf(v) > 1.0f) ? 1 : 0;
    __syncthreads();
    for (int off = 128; off > 0; off >>= 1) {
        if (t < off) s[t] += s[t + off];
        __syncthreads();
    }
    if (t == 0) *flag = (s[0] > 8) ? 1 : 0;
}

// ---------------- float input -> fp32 ws copy (dtype-steered) ----------------
__global__ __launch_bounds__(256) void cvt_auto(const void* __restrict__ src,
                                                float* __restrict__ dst, int n,
                                                const int* __restrict__ flag){
    int i = blockIdx.x * 256 + threadIdx.x;
    if (i >= n) return;
    if (*flag) dst[i] = ((const float*)src)[i];
    else       dst[i] = bfu(((const u16*)src)[i]);
}

__global__ __launch_bounds__(256) void zero_kernel(int* __restrict__ p, int n){
    int i = blockIdx.x * 256 + threadIdx.x;
    if (i < n) p[i] = 0;
}

// ---------------- embed: x[v][h] = embed[nodes[v]][h] ----------------
template<typename T>
__global__ __launch_bounds__(256) void embed_kernel(const int* __restrict__ nodes,
                                                    const float* __restrict__ emb,
                                                    T* __restrict__ x){
    int i = blockIdx.x * 256 + threadIdx.x;
    if (i >= NNODES * HF) return;
    int v = i >> 7, h = i & 127;
    st1(&x[i], emb[nodes[v] * HF + h]);
}

// ---------------- CSR build ----------------
__global__ __launch_bounds__(256) void count_kernel(const int* __restrict__ tgt, int* __restrict__ counts){
    int e = blockIdx.x * 256 + threadIdx.x;
    if (e < NEDGES) atomicAdd(&counts[tgt[e]], 1);
}

__global__ __launch_bounds__(256) void scan1_kernel(const int* __restrict__ counts,
                                                    int* __restrict__ row_ptr,
                                                    int* __restrict__ bsums){
    __shared__ int s[256];
    int t = threadIdx.x;
    int i = blockIdx.x * 256 + t;
    int v = (i < NNODES) ? counts[i] : 0;
    s[t] = v; __syncthreads();
    for (int off = 1; off < 256; off <<= 1) {
        int a = (t >= off) ? s[t - off] : 0;
        __syncthreads();
        s[t] += a;
        __syncthreads();
    }
    if (i < NNODES) row_ptr[i] = s[t] - v;
    if (t == 255) bsums[blockIdx.x] = s[255];
}

__global__ __launch_bounds__(512) void scan2_kernel(const int* __restrict__ bsums,
                                                    int* __restrict__ boffs, int nb){
    __shared__ int s[512];
    int t = threadIdx.x;
    int v = (t < nb) ? bsums[t] : 0;
    s[t] = v; __syncthreads();
    for (int off = 1; off < 512; off <<= 1) {
        int a = (t >= off) ? s[t - off] : 0;
        __syncthreads();
        s[t] += a;
        __syncthreads();
    }
    if (t < nb) boffs[t] = s[t] - v;
}

__global__ __launch_bounds__(256) void scan3_kernel(int* __restrict__ row_ptr,
                                                    const int* __restrict__ boffs,
                                                    int* __restrict__ cursor){
    int i = blockIdx.x * 256 + threadIdx.x;
    if (i < NNODES) {
        int r = row_ptr[i] + boffs[blockIdx.x];
        row_ptr[i] = r;
        cursor[i]  = r;
    }
}

__global__ __launch_bounds__(256) void fill_kernel(const int* __restrict__ src,
                                                   const int* __restrict__ tgt,
                                                   int* __restrict__ cursor,
                                                   int* __restrict__ es){
    int e = blockIdx.x * 256 + threadIdx.x;
    if (e < NEDGES) {
        int pos = atomicAdd(&cursor[tgt[e]], 1);
        es[pos] = src[e];
    }
}

// ---------------- fused conv: M = sig(x@Wg) * sp( sp(x@We1) @ We2 ) ----------------
template<typename T>
__global__ __launch_bounds__(256) void conv_fused(const T* __restrict__ x,
                                                  const float* __restrict__ wg,
                                                  const float* __restrict__ we1,
                                                  const float* __restrict__ we2,
                                                  T* __restrict__ M){
    __shared__ __align__(16) float xs[32 * HF];   // 16 KB
    __shared__ __align__(16) float us[32 * EF];   // 32 KB
    const int t = threadIdx.x;
    const size_t row0 = (size_t)blockIdx.x * 32;

    for (int i = t; i < 32 * HF; i += 256) xs[i] = ld1(&x[row0 * HF + i]);
    __syncthreads();

    // phase B: us = sp(xs @ We1)   [32 x 256]
    {
        const int j0 = (t & 63) * 4;
        const int r0 = (t >> 6) * 8;
        float acc[8][4] = {};
        for (int k = 0; k < HF; k += 4) {
            float4 w0 = *(const float4*)(we1 + (size_t)(k + 0) * EF + j0);
            float4 w1 = *(const float4*)(we1 + (size_t)(k + 1) * EF + j0);
            float4 w2 = *(const float4*)(we1 + (size_t)(k + 2) * EF + j0);
            float4 w3 = *(const float4*)(we1 + (size_t)(k + 3) * EF + j0);
#pragma unroll
            for (int i = 0; i < 8; i++) {
                float4 a = *(const float4*)(xs + (r0 + i) * HF + k);
                acc[i][0] = fmaf(a.x, w0.x, fmaf(a.y, w1.x, fmaf(a.z, w2.x, fmaf(a.w, w3.x, acc[i][0]))));
                acc[i][1] = fmaf(a.x, w0.y, fmaf(a.y, w1.y, fmaf(a.z, w2.y, fmaf(a.w, w3.y, acc[i][1]))));
                acc[i][2] = fmaf(a.x, w0.z, fmaf(a.y, w1.z, fmaf(a.z, w2.z, fmaf(a.w, w3.z, acc[i][2]))));
                acc[i][3] = fmaf(a.x, w0.w, fmaf(a.y, w1.w, fmaf(a.z, w2.w, fmaf(a.w, w3.w, acc[i][3]))));
            }
        }
#pragma unroll
        for (int i = 0; i < 8; i++) {
            us[(r0 + i) * EF + j0 + 0] = sp_f(acc[i][0]);
            us[(r0 + i) * EF + j0 + 1] = sp_f(acc[i][1]);
            us[(r0 + i) * EF + j0 + 2] = sp_f(acc[i][2]);
            us[(r0 + i) * EF + j0 + 3] = sp_f(acc[i][3]);
        }
    }
    __syncthreads();

    // phase C: T = us @ We2, G = xs @ Wg, M = sig(G)*sp(T)   [32 x 128]
    {
        const int j0 = (t & 31) * 4;
        const int r0 = (t >> 5) * 4;
        float aT[4][4] = {};
        float aG[4][4] = {};
        for (int k = 0; k < EF; k += 4) {
            float4 w0 = *(const float4*)(we2 + (size_t)(k + 0) * HF + j0);
            float4 w1 = *(const float4*)(we2 + (size_t)(k + 1) * HF + j0);
            float4 w2 = *(const float4*)(we2 + (size_t)(k + 2) * HF + j0);
            float4 w3 = *(const float4*)(we2 + (size_t)(k + 3) * HF + j0);
#pragma unroll
            for (int i = 0; i < 4; i++) {
                float4 a = *(const float4*)(us + (r0 + i) * EF + k);
                aT[i][0] = fmaf(a.x, w0.x, fmaf(a.y, w1.x, fmaf(a.z, w2.x, fmaf(a.w, w3.x, aT[i][0]))));
                aT[i][1] = fmaf(a.x, w0.y, fmaf(a.y, w1.y, fmaf(a.z, w2.y, fmaf(a.w, w3.y, aT[i][1]))));
                aT[i][2] = fmaf(a.x, w0.z, fmaf(a.y, w1.z, fmaf(a.z, w2.z, fmaf(a.w, w3.z, aT[i][2]))));
                aT[i][3] = fmaf(a.x, w0.w, fmaf(a.y, w1.w, fmaf(a.z, w2.w, fmaf(a.w, w3.w, aT[i][3]))));
            }
        }
        for (int k = 0; k < HF; k += 4) {
            float4 w0 = *(const float4*)(wg + (size_t)(k + 0) * HF + j0);
            float4 w1 = *(const float4*)(wg + (size_t)(k + 1) * HF + j0);
            float4 w2 = *(const float4*)(wg + (size_t)(k + 2) * HF + j0);
            float4 w3 = *(const float4*)(wg + (size_t)(k + 3) * HF + j0);
#pragma unroll
            for (int i = 0; i < 4; i++) {
                float4 a = *(const float4*)(xs + (r0 + i) * HF + k);
                aG[i][0] = fmaf(a.x, w0.x, fmaf(a.y, w1.x, fmaf(a.z, w2.x, fmaf(a.w, w3.x, aG[i][0]))));
                aG[i][1] = fmaf(a.x, w0.y, fmaf(a.y, w1.y, fmaf(a.z, w2.y, fmaf(a.w, w3.y, aG[i][1]))));
                aG[i][2] = fmaf(a.x, w0.z, fmaf(a.y, w1.z, fmaf(a.z, w2.z, fmaf(a.w, w3.z, aG[i][2]))));
                aG[i][3] = fmaf(a.x, w0.w, fmaf(a.y, w1.w, fmaf(a.z, w2.w, fmaf(a.w, w3.w, aG[i][3]))));
            }
        }
#pragma unroll
        for (int i = 0; i < 4; i++) {
            size_t idx = (row0 + r0 + i) * (size_t)HF + j0;
            st1(&M[idx + 0], sig_f(aG[i][0]) * sp_f(aT[i][0]));
            st1(&M[idx + 1], sig_f(aG[i][1]) * sp_f(aT[i][1]));
            st1(&M[idx + 2], sig_f(aG[i][2]) * sp_f(aT[i][2]));
            st1(&M[idx + 3], sig_f(aG[i][3]) * sp_f(aT[i][3]));
        }
    }
}

// ---------------- aggregation: x[v] += sp( sum_{e: tgt=v} M[src[e]] ) ----------------
template<typename T>
__global__ __launch_bounds__(256) void agg_kernel(const T* __restrict__ M,
                                                  const int* __restrict__ row_ptr,
                                                  const int* __restrict__ counts,
                                                  const int* __restrict__ es,
                                                  T* __restrict__ x){
    int v = blockIdx.x * 2 + (threadIdx.x >> 7);
    int h = threadIdx.x & 127;
    if (v >= NNODES) return;
    int start = row_ptr[v], cnt = counts[v];
    float acc = 0.f;
    for (int e = 0; e < cnt; e++) {
        int s = es[start + e];
        acc += ld1(&M[(size_t)s * HF + h]);
    }
    size_t idx = (size_t)v * HF + h;
    st1(&x[idx], ld1(&x[idx]) + sp_f(acc));
}

// ---------------- per-graph node sum (graph_indices sorted) ----------------
template<typename T>
__global__ __launch_bounds__(128) void pool_kernel(const T* __restrict__ x,
                                                   const int* __restrict__ gidx,
                                                   float* __restrict__ xsum){
    int g = blockIdx.x, t = threadIdx.x;
    int lo = 0, hi = NNODES;
    while (lo < hi) { int mid = (lo + hi) >> 1; if (gidx[mid] < g) lo = mid + 1; else hi = mid; }
    int start = lo;
    hi = NNODES;
    while (lo < hi) { int mid = (lo + hi) >> 1; if (gidx[mid] < g + 1) lo = mid + 1; else hi = mid; }
    int end = lo;
    float acc = 0.f;
    for (int v = start; v < end; v++) acc += ld1(&x[(size_t)v * HF + t]);
    xsum[g * HF + t] = acc;
}

// ---------------- head (all-fp32 weights; output format steered by flag) ----------------
__global__ __launch_bounds__(128) void head_kernel(const float* __restrict__ xsum,
                                                   const float* __restrict__ ncnt,
                                                   const float* __restrict__ Wp,
                                                   const float* __restrict__ Wfc1, const float* __restrict__ bfc1,
                                                   const float* __restrict__ Wfc2, const float* __restrict__ bfc2,
                                                   const float* __restrict__ Wr,  const float* __restrict__ br,
                                                   void* __restrict__ out,
                                                   const int* __restrict__ flag){
    int g = blockIdx.x, t = threadIdx.x;
    __shared__ float h0[HF], h1[HF];
    __shared__ float red[2];
    h0[t] = xsum[g * HF + t];
    __syncthreads();
    float cnt = ncnt[g];
    float a = 0.f;
    for (int k = 0; k < HF; k++) a += h0[k] * Wp[k * HF + t];
    float g1 = sp_f(a / cnt);
    h1[t] = g1;
    __syncthreads();
    a = bfc1[t];
    for (int k = 0; k < HF; k++) a += h1[k] * Wfc1[k * HF + t];
    float g2 = sp_f(a);
    __syncthreads();
    h0[t] = g2;
    __syncthreads();
    a = bfc2[t];
    for (int k = 0; k < HF; k++) a += h0[k] * Wfc2[k * HF + t];
    float g3 = sp_f(a);
    float p = g3 * Wr[t];
    for (int off = 32; off > 0; off >>= 1) p += __shfl_down(p, off, 64);
    if ((t & 63) == 0) red[t >> 6] = p;
    __syncthreads();
    if (t == 0) {
        float res = red[0] + red[1] + br[0];
        if (*flag) ((float*)out)[g] = res;
        else       ((u16*)out)[g]  = f2bf(res);
    }
}

template<typename T>
static void run_net(const int* nodes, const int* esrc, const int* etgt, const int* gidx,
                    const float* ncntf, const float* embf,
                    const float* wgf, const float* we1f, const float* we2f,
                    const float* wpf, const float* wfc1f, const float* bfc1f,
                    const float* wfc2f, const float* bfc2f, const float* wrf, const float* brf,
                    T* x, T* M, int* counts, int* row_ptr, int* cursor, int* es,
                    int* bsums, int* boffs, float* xsum, void* out, const int* flag,
                    hipStream_t stream){
    const int NB_SCAN = (NNODES + 255) / 256;
    const int NB_EDGE = (NEDGES + 255) / 256;

    embed_kernel<T><<<(NNODES * HF + 255) / 256, 256, 0, stream>>>(nodes, embf, x);

    zero_kernel<<<NB_SCAN, 256, 0, stream>>>(counts, NNODES);
    count_kernel<<<NB_EDGE, 256, 0, stream>>>(etgt, counts);
    scan1_kernel<<<NB_SCAN, 256, 0, stream>>>(counts, row_ptr, bsums);
    scan2_kernel<<<1, 512, 0, stream>>>(bsums, boffs, NB_SCAN);
    scan3_kernel<<<NB_SCAN, 256, 0, stream>>>(row_ptr, boffs, cursor);
    fill_kernel<<<NB_EDGE, 256, 0, stream>>>(esrc, etgt, cursor, es);

    const int NT = NNODES / 32;   // 3125
    for (int c = 0; c < 3; c++) {
        conv_fused<T><<<NT, 256, 0, stream>>>(x,
            wgf  + (size_t)c * HF * HF,
            we1f + (size_t)c * HF * EF,
            we2f + (size_t)c * EF * HF, M);
        agg_kernel<T><<<NNODES / 2, 256, 0, stream>>>(M, row_ptr, counts, es, x);
    }

    pool_kernel<T><<<NGRAPHS, 128, 0, stream>>>(x, gidx, xsum);
    head_kernel<<<NGRAPHS, 128, 0, stream>>>(xsum, ncntf, wpf, wfc1f, bfc1f,
                                             wfc2f, bfc2f, wrf, brf, out, flag);
}

extern "C" void kernel_launch(void* const* d_in, const int* in_sizes, int n_in,
                              void* d_out, int out_size, void* d_ws, size_t ws_size,
                              hipStream_t stream) {
    const int* nodes = (const int*)d_in[0];
    const int* esrc  = (const int*)d_in[1];
    const int* etgt  = (const int*)d_in[2];
    const int* gidx  = (const int*)d_in[3];

    // sizes of float inputs (element counts)
    const int nNC   = NGRAPHS;
    const int nEMB  = 90 * HF;
    const int nWG   = 3 * HF * HF;
    const int nWE1  = 3 * HF * EF;
    const int nWE2  = 3 * EF * HF;
    const int nWP   = HF * HF;
    const int nFC1  = HF * 128;
    const int nB1   = 128;
    const int nFC2  = 128 * 128;
    const int nB2   = 128;
    const int nWR   = 128;
    const int nBR   = 1;

    size_t off = 0;
    char* w = (char*)d_ws;
    auto take = [&](size_t bytes) -> void* {
        void* p = w + off;
        off = (off + bytes + 255) & ~(size_t)255;
        return p;
    };

    int*   flag  = (int*)take(256);
    float* ncntf = (float*)take((size_t)nNC  * 4);
    float* embf  = (float*)take((size_t)nEMB * 4);
    float* wgf   = (float*)take((size_t)nWG  * 4);
    float* we1f  = (float*)take((size_t)nWE1 * 4);
    float* we2f  = (float*)take((size_t)nWE2 * 4);
    float* wpf   = (float*)take((size_t)nWP  * 4);
    float* wfc1f = (float*)take((size_t)nFC1 * 4);
    float* bfc1f = (float*)take((size_t)nB1  * 4);
    float* wfc2f = (float*)take((size_t)nFC2 * 4);
    float* bfc2f = (float*)take((size_t)nB2  * 4);
    float* wrf   = (float*)take((size_t)nWR  * 4);
    float* brf   = (float*)take((size_t)nBR  * 4);
    int* counts  = (int*)take((size_t)NNODES * 4);
    int* row_ptr = (int*)take((size_t)NNODES * 4);
    int* cursor  = (int*)take((size_t)NNODES * 4);
    int* es      = (int*)take((size_t)NEDGES * 4);
    int* bsums   = (int*)take(2048);
    int* boffs   = (int*)take(2048);
    float* xsum  = (float*)take((size_t)NGRAPHS * HF * 4);

    // x and M last: choose their storage precision from remaining ws space
    const size_t remain = (ws_size > off) ? ws_size - off : 0;
    const bool F32 = remain >= (size_t)NNODES * HF * 2 * 4 + 1024;
    const size_t esz = F32 ? 4 : 2;
    void* xb = take((size_t)NNODES * HF * esz);
    void* Mb = take((size_t)NNODES * HF * esz);

    // detect storage dtype of float inputs (device-side, capture-safe)
    detect_kernel<<<1, 256, 0, stream>>>((const u16*)d_in[5], flag);

    // convert all float inputs to fp32 ws copies
    auto cvt = [&](const void* src, float* dst, int n) {
        cvt_auto<<<(n + 255) / 256, 256, 0, stream>>>(src, dst, n, flag);
    };
    cvt(d_in[4],  ncntf, nNC);
    cvt(d_in[5],  embf,  nEMB);
    cvt(d_in[6],  wgf,   nWG);
    cvt(d_in[7],  we1f,  nWE1);
    cvt(d_in[8],  we2f,  nWE2);
    cvt(d_in[9],  wpf,   nWP);
    cvt(d_in[10], wfc1f, nFC1);
    cvt(d_in[11], bfc1f, nB1);
    cvt(d_in[12], wfc2f, nFC2);
    cvt(d_in[13], bfc2f, nB2);
    cvt(d_in[14], wrf,   nWR);
    cvt(d_in[15], brf,   nBR);

    if (F32) {
        run_net<float>(nodes, esrc, etgt, gidx, ncntf, embf, wgf, we1f, we2f,
                       wpf, wfc1f, bfc1f, wfc2f, bfc2f, wrf, brf,
                       (float*)xb, (float*)Mb, counts, row_ptr, cursor, es,
                       bsums, boffs, xsum, d_out, flag, stream);
    } else {
        run_net<u16>(nodes, esrc, etgt, gidx, ncntf, embf, wgf, we1f, we2f,
                     wpf, wfc1f, bfc1f, wfc2f, bfc2f, wrf, brf,
                     (u16*)xb, (u16*)Mb, counts, row_ptr, cursor, es,
                     bsums, boffs, xsum, d_out, flag, stream);
    }
}

// Round 4
// 951.021 us; speedup vs baseline: 1.7124x; 1.7124x over previous
//
#include <hip/hip_runtime.h>
#include <hip/hip_bf16.h>

typedef unsigned short u16;
typedef __attribute__((ext_vector_type(8))) short short8;
typedef __attribute__((ext_vector_type(4))) float f32x4;

#define NNODES 100000
#define NEDGES 600000
#define NGRAPHS 512
#define HF 128
#define EF 256
#define XS_LD 136   // 128 + 8 pad, bf16 units
#define US_LD 264   // 256 + 8 pad

__device__ __forceinline__ float bfu(u16 u){ return __uint_as_float(((unsigned)u) << 16); }
__device__ __forceinline__ float sp_f(float x){ return fmaxf(x, 0.f) + log1pf(expf(-fabsf(x))); }
__device__ __forceinline__ float sig_f(float x){ return 1.f / (1.f + expf(-x)); }
__device__ __forceinline__ u16 f2bf(float f){
    unsigned u = __float_as_uint(f);
    unsigned r = (u + 0x7fff + ((u >> 16) & 1)) >> 16;
    return (u16)r;
}

// ---------------- input dtype detection (bf16 vs fp32 storage) ----------------
__global__ __launch_bounds__(256) void detect_kernel(const u16* __restrict__ probe,
                                                     int* __restrict__ flag){
    __shared__ int s[256];
    int t = threadIdx.x;
    float v = bfu(probe[t]);
    s[t] = (fabsf(v) > 1.0f) ? 1 : 0;
    __syncthreads();
    for (int off = 128; off > 0; off >>= 1) {
        if (t < off) s[t] += s[t + off];
        __syncthreads();
    }
    if (t == 0) *flag = (s[0] > 8) ? 1 : 0;
}

__global__ __launch_bounds__(256) void cvt_auto(const void* __restrict__ src,
                                                float* __restrict__ dst, int n,
                                                const int* __restrict__ flag){
    int i = blockIdx.x * 256 + threadIdx.x;
    if (i >= n) return;
    if (*flag) dst[i] = ((const float*)src)[i];
    else       dst[i] = bfu(((const u16*)src)[i]);
}

__global__ __launch_bounds__(256) void zero_kernel(int* __restrict__ p, int n){
    int i = blockIdx.x * 256 + threadIdx.x;
    if (i < n) p[i] = 0;
}

// ---------------- repack weight [K][N] fp32 -> B-fragment-packed bf16 ----------------
// P layout: [kt][nt][lane][8], kt = K/32, nt = N/16.
// lane l holds B[k = kt*32 + (l>>4)*8 + j][n = nt*16 + (l&15)], j = 0..7
__global__ __launch_bounds__(256) void repack_b(const float* __restrict__ W,
                                                u16* __restrict__ P, int K, int N){
    int i = blockIdx.x * 256 + threadIdx.x;
    if (i >= K * N) return;
    int j = i & 7;
    int lane = (i >> 3) & 63;
    int rest = i >> 9;
    int NT = N >> 4;
    int nt = rest % NT, kt = rest / NT;
    int k = kt * 32 + (lane >> 4) * 8 + j;
    int n = nt * 16 + (lane & 15);
    P[i] = f2bf(W[k * N + n]);
}

// ---------------- embed: x[v][h] = embed[nodes[v]][h]  (x stored bf16) ----------------
__global__ __launch_bounds__(256) void embed_kernel(const int* __restrict__ nodes,
                                                    const float* __restrict__ emb,
                                                    u16* __restrict__ x){
    int i = blockIdx.x * 256 + threadIdx.x;       // dword index
    if (i >= NNODES * 64) return;
    int v = i >> 6, c = i & 63;
    const float* row = emb + nodes[v] * HF + c * 2;
    unsigned lo = f2bf(row[0]), hi = f2bf(row[1]);
    ((unsigned*)x)[i] = lo | (hi << 16);
}

// ---------------- CSR build ----------------
__global__ __launch_bounds__(256) void count_kernel(const int* __restrict__ tgt, int* __restrict__ counts){
    int e = blockIdx.x * 256 + threadIdx.x;
    if (e < NEDGES) atomicAdd(&counts[tgt[e]], 1);
}

__global__ __launch_bounds__(256) void scan1_kernel(const int* __restrict__ counts,
                                                    int* __restrict__ row_ptr,
                                                    int* __restrict__ bsums){
    __shared__ int s[256];
    int t = threadIdx.x;
    int i = blockIdx.x * 256 + t;
    int v = (i < NNODES) ? counts[i] : 0;
    s[t] = v; __syncthreads();
    for (int off = 1; off < 256; off <<= 1) {
        int a = (t >= off) ? s[t - off] : 0;
        __syncthreads();
        s[t] += a;
        __syncthreads();
    }
    if (i < NNODES) row_ptr[i] = s[t] - v;
    if (t == 255) bsums[blockIdx.x] = s[255];
}

__global__ __launch_bounds__(512) void scan2_kernel(const int* __restrict__ bsums,
                                                    int* __restrict__ boffs, int nb){
    __shared__ int s[512];
    int t = threadIdx.x;
    int v = (t < nb) ? bsums[t] : 0;
    s[t] = v; __syncthreads();
    for (int off = 1; off < 512; off <<= 1) {
        int a = (t >= off) ? s[t - off] : 0;
        __syncthreads();
        s[t] += a;
        __syncthreads();
    }
    if (t < nb) boffs[t] = s[t] - v;
}

__global__ __launch_bounds__(256) void scan3_kernel(int* __restrict__ row_ptr,
                                                    const int* __restrict__ boffs,
                                                    int* __restrict__ cursor){
    int i = blockIdx.x * 256 + threadIdx.x;
    if (i < NNODES) {
        int r = row_ptr[i] + boffs[blockIdx.x];
        row_ptr[i] = r;
        cursor[i]  = r;
    }
}

__global__ __launch_bounds__(256) void fill_kernel(const int* __restrict__ src,
                                                   const int* __restrict__ tgt,
                                                   int* __restrict__ cursor,
                                                   int* __restrict__ es){
    int e = blockIdx.x * 256 + threadIdx.x;
    if (e < NEDGES) {
        int pos = atomicAdd(&cursor[tgt[e]], 1);
        es[pos] = src[e];
    }
}

// ---------------- fused conv via MFMA: M = sig(x@Wg) * sp( sp(x@We1) @ We2 ) ----------------
// block = 64 node rows, 4 waves. Waves split columns so each weight byte is
// read once per block. x, U staged in LDS with +8 bf16 pad (2-way bank = free).
__global__ __launch_bounds__(256) void conv_mfma(const u16* __restrict__ x,
                                                 const u16* __restrict__ pwg,
                                                 const u16* __restrict__ pwe1,
                                                 const u16* __restrict__ pwe2,
                                                 u16* __restrict__ M){
    __shared__ u16 xs[64 * XS_LD];   // 17,408 B
    __shared__ u16 us[64 * US_LD];   // 33,792 B
    const int t = threadIdx.x;
    const int w = t >> 6, lane = t & 63;
    const int quad = lane >> 4, mrow = lane & 15;
    const long row0 = (long)blockIdx.x * 64;

    // stage x tile (64 rows x 128 bf16), zero-pad past NNODES
    for (int c = t; c < 1024; c += 256) {          // 16 dwordx4 chunks per row
        int r = c >> 4, col8 = c & 15;
        long node = row0 + r;
        uint4 v = make_uint4(0u, 0u, 0u, 0u);
        if (node < NNODES) v = *(const uint4*)(x + node * HF + col8 * 8);
        *(uint4*)(&xs[r * XS_LD + col8 * 8]) = v;
    }
    __syncthreads();

    // ---- phase U: us = sp(xs @ We1), wave w owns col-tiles w*4 .. w*4+3 ----
    {
        short8 bfr[4][4];                          // [ntl][kt]
#pragma unroll
        for (int ntl = 0; ntl < 4; ntl++) {
            int nt = w * 4 + ntl;
#pragma unroll
            for (int kt = 0; kt < 4; kt++)
                bfr[ntl][kt] = *(const short8*)(pwe1 + (((kt * 16 + nt) * 64 + lane) << 3));
        }
#pragma unroll
        for (int rt = 0; rt < 4; rt++) {
            short8 afr[4];
#pragma unroll
            for (int kt = 0; kt < 4; kt++)
                afr[kt] = *(const short8*)(&xs[(rt * 16 + mrow) * XS_LD + kt * 32 + quad * 8]);
#pragma unroll
            for (int ntl = 0; ntl < 4; ntl++) {
                int nt = w * 4 + ntl;
                f32x4 acc = {0.f, 0.f, 0.f, 0.f};
#pragma unroll
                for (int kt = 0; kt < 4; kt++)
                    acc = __builtin_amdgcn_mfma_f32_16x16x32_bf16(afr[kt], bfr[ntl][kt], acc, 0, 0, 0);
#pragma unroll
                for (int r = 0; r < 4; r++)
                    us[(rt * 16 + quad * 4 + r) * US_LD + nt * 16 + mrow] = f2bf(sp_f(acc[r]));
            }
        }
    }
    __syncthreads();

    // ---- phase T+G: T = us @ We2 (K=256), G = xs @ Wg (K=128); wave w owns col-tiles {w*2, w*2+1} ----
    {
        short8 bT[2][8], bG[2][4];
#pragma unroll
        for (int c = 0; c < 2; c++) {
            int nt = w * 2 + c;
#pragma unroll
            for (int kt = 0; kt < 8; kt++)
                bT[c][kt] = *(const short8*)(pwe2 + (((kt * 8 + nt) * 64 + lane) << 3));
#pragma unroll
            for (int kt = 0; kt < 4; kt++)
                bG[c][kt] = *(const short8*)(pwg + (((kt * 8 + nt) * 64 + lane) << 3));
        }
#pragma unroll
        for (int rt = 0; rt < 4; rt++) {
            short8 aU[8], aX[4];
#pragma unroll
            for (int kt = 0; kt < 8; kt++)
                aU[kt] = *(const short8*)(&us[(rt * 16 + mrow) * US_LD + kt * 32 + quad * 8]);
#pragma unroll
            for (int kt = 0; kt < 4; kt++)
                aX[kt] = *(const short8*)(&xs[(rt * 16 + mrow) * XS_LD + kt * 32 + quad * 8]);
#pragma unroll
            for (int c = 0; c < 2; c++) {
                int nt = w * 2 + c;
                f32x4 accT = {0.f, 0.f, 0.f, 0.f};
                f32x4 accG = {0.f, 0.f, 0.f, 0.f};
#pragma unroll
                for (int kt = 0; kt < 8; kt++)
                    accT = __builtin_amdgcn_mfma_f32_16x16x32_bf16(aU[kt], bT[c][kt], accT, 0, 0, 0);
#pragma unroll
                for (int kt = 0; kt < 4; kt++)
                    accG = __builtin_amdgcn_mfma_f32_16x16x32_bf16(aX[kt], bG[c][kt], accG, 0, 0, 0);
#pragma unroll
                for (int r = 0; r < 4; r++) {
                    long node = row0 + rt * 16 + quad * 4 + r;
                    if (node < NNODES)
                        M[node * HF + nt * 16 + mrow] = f2bf(sig_f(accG[r]) * sp_f(accT[r]));
                }
            }
        }
    }
}

// ---------------- aggregation: x[v] += sp( sum_{e: tgt=v} M[src[e]] )  (bf16, dword lanes) ----------------
__global__ __launch_bounds__(256) void agg_kernel(const u16* __restrict__ M,
                                                  const int* __restrict__ row_ptr,
                                                  const int* __restrict__ counts,
                                                  const int* __restrict__ es,
                                                  u16* __restrict__ x){
    int v = blockIdx.x * 4 + (threadIdx.x >> 6);
    int c = threadIdx.x & 63;                     // dword lane (2 bf16)
    if (v >= NNODES) return;
    int start = row_ptr[v], cnt = counts[v];
    float a0 = 0.f, a1 = 0.f;
    const unsigned* Mu = (const unsigned*)M;
    for (int e = 0; e < cnt; e++) {
        int s = es[start + e];
        unsigned u = Mu[s * 64 + c];
        a0 += bfu((u16)u);
        a1 += bfu((u16)(u >> 16));
    }
    unsigned* xu = (unsigned*)x;
    unsigned xv = xu[v * 64 + c];
    float x0 = bfu((u16)xv) + sp_f(a0);
    float x1 = bfu((u16)(xv >> 16)) + sp_f(a1);
    xu[v * 64 + c] = (unsigned)f2bf(x0) | ((unsigned)f2bf(x1) << 16);
}

// ---------------- per-graph node sum (graph_indices sorted) ----------------
__global__ __launch_bounds__(64) void pool_kernel(const u16* __restrict__ x,
                                                  const int* __restrict__ gidx,
                                                  float* __restrict__ xsum){
    int g = blockIdx.x, t = threadIdx.x;          // t = dword col
    int lo = 0, hi = NNODES;
    while (lo < hi) { int mid = (lo + hi) >> 1; if (gidx[mid] < g) lo = mid + 1; else hi = mid; }
    int start = lo;
    hi = NNODES;
    while (lo < hi) { int mid = (lo + hi) >> 1; if (gidx[mid] < g + 1) lo = mid + 1; else hi = mid; }
    int end = lo;
    float a0 = 0.f, a1 = 0.f;
    const unsigned* xu = (const unsigned*)x;
    for (int v = start; v < end; v++) {
        unsigned u = xu[v * 64 + t];
        a0 += bfu((u16)u);
        a1 += bfu((u16)(u >> 16));
    }
    xsum[g * HF + t * 2 + 0] = a0;
    xsum[g * HF + t * 2 + 1] = a1;
}

// ---------------- head (fp32 ws weights; output format steered by flag) ----------------
__global__ __launch_bounds__(128) void head_kernel(const float* __restrict__ xsum,
                                                   const float* __restrict__ ncnt,
                                                   const float* __restrict__ Wp,
                                                   const float* __restrict__ Wfc1, const float* __restrict__ bfc1,
                                                   const float* __restrict__ Wfc2, const float* __restrict__ bfc2,
                                                   const float* __restrict__ Wr,  const float* __restrict__ br,
                                                   void* __restrict__ out,
                                                   const int* __restrict__ flag){
    int g = blockIdx.x, t = threadIdx.x;
    __shared__ float h0[HF], h1[HF];
    __shared__ float red[2];
    h0[t] = xsum[g * HF + t];
    __syncthreads();
    float cnt = ncnt[g];
    float a = 0.f;
    for (int k = 0; k < HF; k++) a += h0[k] * Wp[k * HF + t];
    float g1 = sp_f(a / cnt);
    h1[t] = g1;
    __syncthreads();
    a = bfc1[t];
    for (int k = 0; k < HF; k++) a += h1[k] * Wfc1[k * HF + t];
    float g2 = sp_f(a);
    __syncthreads();
    h0[t] = g2;
    __syncthreads();
    a = bfc2[t];
    for (int k = 0; k < HF; k++) a += h0[k] * Wfc2[k * HF + t];
    float g3 = sp_f(a);
    float p = g3 * Wr[t];
    for (int off = 32; off > 0; off >>= 1) p += __shfl_down(p, off, 64);
    if ((t & 63) == 0) red[t >> 6] = p;
    __syncthreads();
    if (t == 0) {
        float res = red[0] + red[1] + br[0];
        if (*flag) ((float*)out)[g] = res;
        else       ((u16*)out)[g]  = f2bf(res);
    }
}

extern "C" void kernel_launch(void* const* d_in, const int* in_sizes, int n_in,
                              void* d_out, int out_size, void* d_ws, size_t ws_size,
                              hipStream_t stream) {
    const int* nodes = (const int*)d_in[0];
    const int* esrc  = (const int*)d_in[1];
    const int* etgt  = (const int*)d_in[2];
    const int* gidx  = (const int*)d_in[3];

    const int nNC   = NGRAPHS;
    const int nEMB  = 90 * HF;
    const int nWG   = 3 * HF * HF;
    const int nWE1  = 3 * HF * EF;
    const int nWE2  = 3 * EF * HF;
    const int nWP   = HF * HF;
    const int nFC1  = HF * 128;
    const int nB1   = 128;
    const int nFC2  = 128 * 128;
    const int nB2   = 128;
    const int nWR   = 128;
    const int nBR   = 1;

    size_t off = 0;
    char* w = (char*)d_ws;
    auto take = [&](size_t bytes) -> void* {
        void* p = w + off;
        off = (off + bytes + 255) & ~(size_t)255;
        return p;
    };

    int*   flag  = (int*)take(256);
    float* ncntf = (float*)take((size_t)nNC  * 4);
    float* embf  = (float*)take((size_t)nEMB * 4);
    float* wgf   = (float*)take((size_t)nWG  * 4);
    float* we1f  = (float*)take((size_t)nWE1 * 4);
    float* we2f  = (float*)take((size_t)nWE2 * 4);
    float* wpf   = (float*)take((size_t)nWP  * 4);
    float* wfc1f = (float*)take((size_t)nFC1 * 4);
    float* bfc1f = (float*)take((size_t)nB1  * 4);
    float* wfc2f = (float*)take((size_t)nFC2 * 4);
    float* bfc2f = (float*)take((size_t)nB2  * 4);
    float* wrf   = (float*)take((size_t)nWR  * 4);
    float* brf   = (float*)take((size_t)nBR  * 4);
    u16* pwg     = (u16*)take((size_t)nWG  * 2);   // packed bf16 B-fragments
    u16* pwe1    = (u16*)take((size_t)nWE1 * 2);
    u16* pwe2    = (u16*)take((size_t)nWE2 * 2);
    int* counts  = (int*)take((size_t)NNODES * 4);
    int* row_ptr = (int*)take((size_t)NNODES * 4);
    int* cursor  = (int*)take((size_t)NNODES * 4);
    int* es      = (int*)take((size_t)NEDGES * 4);
    int* bsums   = (int*)take(2048);
    int* boffs   = (int*)take(2048);
    float* xsum  = (float*)take((size_t)NGRAPHS * HF * 4);
    u16* x       = (u16*)take((size_t)NNODES * HF * 2);
    u16* M       = (u16*)take((size_t)NNODES * HF * 2);

    // detect storage dtype (capture-safe, device-side)
    detect_kernel<<<1, 256, 0, stream>>>((const u16*)d_in[5], flag);

    auto cvt = [&](const void* src, float* dst, int n) {
        cvt_auto<<<(n + 255) / 256, 256, 0, stream>>>(src, dst, n, flag);
    };
    cvt(d_in[4],  ncntf, nNC);
    cvt(d_in[5],  embf,  nEMB);
    cvt(d_in[6],  wgf,   nWG);
    cvt(d_in[7],  we1f,  nWE1);
    cvt(d_in[8],  we2f,  nWE2);
    cvt(d_in[9],  wpf,   nWP);
    cvt(d_in[10], wfc1f, nFC1);
    cvt(d_in[11], bfc1f, nB1);
    cvt(d_in[12], wfc2f, nFC2);
    cvt(d_in[13], bfc2f, nB2);
    cvt(d_in[14], wrf,   nWR);
    cvt(d_in[15], brf,   nBR);

    // repack conv weights into MFMA B-fragment order (per conv)
    for (int c = 0; c < 3; c++) {
        repack_b<<<(HF*HF + 255)/256, 256, 0, stream>>>(wgf  + (size_t)c*HF*HF, pwg  + (size_t)c*HF*HF, HF, HF);
        repack_b<<<(HF*EF + 255)/256, 256, 0, stream>>>(we1f + (size_t)c*HF*EF, pwe1 + (size_t)c*HF*EF, HF, EF);
        repack_b<<<(EF*HF + 255)/256, 256, 0, stream>>>(we2f + (size_t)c*EF*HF, pwe2 + (size_t)c*EF*HF, EF, HF);
    }

    const int NB_SCAN = (NNODES + 255) / 256;
    const int NB_EDGE = (NEDGES + 255) / 256;

    embed_kernel<<<(NNODES * 64 + 255) / 256, 256, 0, stream>>>(nodes, embf, x);

    zero_kernel<<<NB_SCAN, 256, 0, stream>>>(counts, NNODES);
    count_kernel<<<NB_EDGE, 256, 0, stream>>>(etgt, counts);
    scan1_kernel<<<NB_SCAN, 256, 0, stream>>>(counts, row_ptr, bsums);
    scan2_kernel<<<1, 512, 0, stream>>>(bsums, boffs, NB_SCAN);
    scan3_kernel<<<NB_SCAN, 256, 0, stream>>>(row_ptr, boffs, cursor);
    fill_kernel<<<NB_EDGE, 256, 0, stream>>>(esrc, etgt, cursor, es);

    const int NBC = (NNODES + 63) / 64;   // 1563
    for (int c = 0; c < 3; c++) {
        conv_mfma<<<NBC, 256, 0, stream>>>(x,
            pwg  + (size_t)c * HF * HF,
            pwe1 + (size_t)c * HF * EF,
            pwe2 + (size_t)c * EF * HF, M);
        agg_kernel<<<(NNODES + 3) / 4, 256, 0, stream>>>(M, row_ptr, counts, es, x);
    }

    pool_kernel<<<NGRAPHS, 64, 0, stream>>>(x, gidx, xsum);
    head_kernel<<<NGRAPHS, 128, 0, stream>>>(xsum, ncntf, wpf, wfc1f, bfc1f,
                                             wfc2f, bfc2f, wrf, brf, d_out, flag);
}

// Round 5
// 627.216 us; speedup vs baseline: 2.5965x; 1.5163x over previous
//
#include <hip/hip_runtime.h>
#include <hip/hip_bf16.h>

typedef unsigned short u16;
typedef __attribute__((ext_vector_type(8))) short short8;
typedef __attribute__((ext_vector_type(4))) float f32x4;

#define NNODES 100000
#define NEDGES 600000
#define NGRAPHS 512
#define HF 128
#define EF 256
#define XS_LD 136   // 128 + 8 pad (16B-aligned rows)
#define US_LD 264   // 256 + 8 pad

__device__ __forceinline__ float bfu(u16 u){ return __uint_as_float(((unsigned)u) << 16); }
__device__ __forceinline__ u16 f2bf(float f){
    unsigned u = __float_as_uint(f);
    unsigned r = (u + 0x7fff + ((u >> 16) & 1)) >> 16;
    return (u16)r;
}
__device__ __forceinline__ unsigned pack2(float a, float b){
    return (unsigned)f2bf(a) | ((unsigned)f2bf(b) << 16);
}

#if __has_builtin(__builtin_amdgcn_rcpf)
#define RCP1(x) __builtin_amdgcn_rcpf(x)
#else
#define RCP1(x) (1.f / (x))
#endif

// fast softplus / sigmoid via native v_exp/v_log/v_rcp (~1e-7 abs err)
__device__ __forceinline__ float sp_f(float x){
    return fmaxf(x, 0.f) + __logf(1.f + __expf(-fabsf(x)));
}
__device__ __forceinline__ float sig_f(float x){
    return RCP1(1.f + __expf(-x));
}
// flag-steered load of a "float" input that may be stored bf16 or fp32
__device__ __forceinline__ float lf(const void* p, long i, bool f32){
    return f32 ? ((const float*)p)[i] : bfu(((const u16*)p)[i]);
}

// ---------------- input dtype detection (bf16 vs fp32 storage) ----------------
__global__ __launch_bounds__(256) void detect_kernel(const u16* __restrict__ probe,
                                                     int* __restrict__ flag){
    __shared__ int s[256];
    int t = threadIdx.x;
    float v = bfu(probe[t]);
    s[t] = (fabsf(v) > 1.0f) ? 1 : 0;
    __syncthreads();
    for (int off = 128; off > 0; off >>= 1) {
        if (t < off) s[t] += s[t + off];
        __syncthreads();
    }
    if (t == 0) *flag = (s[0] > 8) ? 1 : 0;
}

// ---------------- repack all conv weights -> MFMA fragment order (bf16) ----------------
// P layout per [K][N] weight: [kt][nt][lane][8]; lane l holds
// W[k = kt*32 + (l>>4)*8 + j][n = nt*16 + (l&15)], j=0..7.
// Same buffer serves as B-frags for W and as A-frags for W^T.
__global__ __launch_bounds__(256) void repack_all(const void* __restrict__ wg,
                                                  const void* __restrict__ we1,
                                                  const void* __restrict__ we2,
                                                  u16* __restrict__ pwg,
                                                  u16* __restrict__ pwe1,
                                                  u16* __restrict__ pwe2,
                                                  const int* __restrict__ flag){
    int i = blockIdx.x * 256 + threadIdx.x;
    if (i >= 3 * 81920) return;
    bool f32 = *flag != 0;
    int c = i / 81920, r = i % 81920;
    const void* src; u16* dst; int N, KN, l;
    if (r < 16384)      { src = wg;  dst = pwg;  N = HF; KN = 16384; l = r; }
    else if (r < 49152) { src = we1; dst = pwe1; N = EF; KN = 32768; l = r - 16384; }
    else                { src = we2; dst = pwe2; N = HF; KN = 32768; l = r - 49152; }
    int j = l & 7, lane = (l >> 3) & 63, rest = l >> 9;
    int NT = N >> 4, nt = rest % NT, kt = rest / NT;
    int k = kt * 32 + (lane >> 4) * 8 + j;
    int n = nt * 16 + (lane & 15);
    long base = (long)c * KN;
    dst[base + l] = f2bf(lf(src, base + (long)k * N + n, f32));
}

// ---------------- embed: x[v][h] = embed[nodes[v]][h]  (x stored bf16) ----------------
__global__ __launch_bounds__(256) void embed_kernel(const int* __restrict__ nodes,
                                                    const void* __restrict__ emb,
                                                    u16* __restrict__ x,
                                                    const int* __restrict__ flag){
    int i = blockIdx.x * 256 + threadIdx.x;       // dword index
    if (i >= NNODES * 64) return;
    bool f32 = *flag != 0;
    int v = i >> 6, c = i & 63;
    long base = (long)nodes[v] * HF + c * 2;
    ((unsigned*)x)[i] = pack2(lf(emb, base, f32), lf(emb, base + 1, f32));
}

// ---------------- CSR build ----------------
__global__ __launch_bounds__(256) void count_kernel(const int* __restrict__ tgt, int* __restrict__ counts){
    int e = blockIdx.x * 256 + threadIdx.x;
    if (e < NEDGES) atomicAdd(&counts[tgt[e]], 1);
}

__global__ __launch_bounds__(256) void scan1_kernel(const int* __restrict__ counts,
                                                    int* __restrict__ row_ptr,
                                                    int* __restrict__ bsums){
    __shared__ int s[256];
    int t = threadIdx.x;
    int i = blockIdx.x * 256 + t;
    int v = (i < NNODES) ? counts[i] : 0;
    s[t] = v; __syncthreads();
    for (int off = 1; off < 256; off <<= 1) {
        int a = (t >= off) ? s[t - off] : 0;
        __syncthreads();
        s[t] += a;
        __syncthreads();
    }
    if (i < NNODES) row_ptr[i] = s[t] - v;
    if (t == 255) bsums[blockIdx.x] = s[255];
}

__global__ __launch_bounds__(512) void scan2_kernel(const int* __restrict__ bsums,
                                                    int* __restrict__ boffs, int nb){
    __shared__ int s[512];
    int t = threadIdx.x;
    int v = (t < nb) ? bsums[t] : 0;
    s[t] = v; __syncthreads();
    for (int off = 1; off < 512; off <<= 1) {
        int a = (t >= off) ? s[t - off] : 0;
        __syncthreads();
        s[t] += a;
        __syncthreads();
    }
    if (t < nb) boffs[t] = s[t] - v;
}

__global__ __launch_bounds__(256) void scan3_kernel(int* __restrict__ row_ptr,
                                                    const int* __restrict__ boffs,
                                                    int* __restrict__ cursor){
    int i = blockIdx.x * 256 + threadIdx.x;
    if (i < NNODES) {
        int r = row_ptr[i] + boffs[blockIdx.x];
        row_ptr[i] = r;
        cursor[i]  = r;
    }
}

__global__ __launch_bounds__(256) void fill_kernel(const int* __restrict__ src,
                                                   const int* __restrict__ tgt,
                                                   int* __restrict__ cursor,
                                                   int* __restrict__ es){
    int e = blockIdx.x * 256 + threadIdx.x;
    if (e < NEDGES) {
        int pos = atomicAdd(&cursor[tgt[e]], 1);
        es[pos] = src[e];
    }
}

// ---------------- fused conv via transposed MFMA ----------------
// Computes M = sig(x@Wg) * sp( sp(x@We1)@We2 ) for 64 nodes per block.
// All products computed transposed (features = M-dim, nodes = N-dim) so the
// C-layout gives each lane 4 consecutive features of one node -> b64 stores.
// Packed weights act as A-fragments of W^T (layout identity with B-of-W).
__global__ __launch_bounds__(256) void conv_mfma(const u16* __restrict__ x,
                                                 const u16* __restrict__ pwg,
                                                 const u16* __restrict__ pwe1,
                                                 const u16* __restrict__ pwe2,
                                                 u16* __restrict__ M){
    __shared__ u16 xs[64 * XS_LD];   // 17,408 B
    __shared__ u16 us[64 * US_LD];   // 33,792 B
    const int t = threadIdx.x;
    const int w = t >> 6, lane = t & 63;
    const int quad = lane >> 4, nr = lane & 15;
    const long row0 = (long)blockIdx.x * 64;

    // stage x tile (64 rows x 128 bf16), zero-pad past NNODES
    for (int c = t; c < 1024; c += 256) {
        int r = c >> 4, c8 = c & 15;
        long node = row0 + r;
        uint4 v = make_uint4(0u, 0u, 0u, 0u);
        if (node < NNODES) v = *(const uint4*)(x + node * HF + c8 * 8);
        *(uint4*)(&xs[r * XS_LD + c8 * 8]) = v;
    }
    __syncthreads();

    // ---- phase U: us[node][ef] = sp( (We1^T @ x^T)[ef][node] ) ----
    // wave w owns ef-tiles et = w*4 .. w*4+3 (A-frags hoisted: min weight traffic)
    {
        short8 A[4][4];                            // [etl][kt]
#pragma unroll
        for (int etl = 0; etl < 4; etl++) {
            int et = w * 4 + etl;
#pragma unroll
            for (int kt = 0; kt < 4; kt++)
                A[etl][kt] = *(const short8*)(pwe1 + (((kt * 16 + et) * 64 + lane) << 3));
        }
#pragma unroll
        for (int nt = 0; nt < 4; nt++) {
            short8 bx[4];                          // x^T B-frags: node = nt*16+nr
#pragma unroll
            for (int kt = 0; kt < 4; kt++)
                bx[kt] = *(const short8*)(&xs[(nt * 16 + nr) * XS_LD + kt * 32 + quad * 8]);
#pragma unroll
            for (int etl = 0; etl < 4; etl++) {
                f32x4 acc = {0.f, 0.f, 0.f, 0.f};
#pragma unroll
                for (int kt = 0; kt < 4; kt++)
                    acc = __builtin_amdgcn_mfma_f32_16x16x32_bf16(A[etl][kt], bx[kt], acc, 0, 0, 0);
                // lane holds node = nt*16+nr, ef = (w*4+etl)*16 + quad*4 + r
                uint2 d;
                d.x = pack2(sp_f(acc[0]), sp_f(acc[1]));
                d.y = pack2(sp_f(acc[2]), sp_f(acc[3]));
                *(uint2*)(&us[(nt * 16 + nr) * US_LD + (w * 4 + etl) * 16 + quad * 4]) = d;
            }
        }
    }
    __syncthreads();

    // ---- phase C: M[node][h] = sig((Wg^T@x^T)[h][node]) * sp((We2^T@U^T)[h][node]) ----
    // wave w owns h-tiles et = w*2, w*2+1
    {
#pragma unroll
        for (int c = 0; c < 2; c++) {
            int et = w * 2 + c;
            short8 AT[8], AG[4];
#pragma unroll
            for (int kt = 0; kt < 8; kt++)
                AT[kt] = *(const short8*)(pwe2 + (((kt * 8 + et) * 64 + lane) << 3));
#pragma unroll
            for (int kt = 0; kt < 4; kt++)
                AG[kt] = *(const short8*)(pwg + (((kt * 8 + et) * 64 + lane) << 3));
#pragma unroll
            for (int nt = 0; nt < 4; nt++) {
                f32x4 aT = {0.f, 0.f, 0.f, 0.f};
                f32x4 aG = {0.f, 0.f, 0.f, 0.f};
#pragma unroll
                for (int kt = 0; kt < 8; kt++) {
                    short8 bu = *(const short8*)(&us[(nt * 16 + nr) * US_LD + kt * 32 + quad * 8]);
                    aT = __builtin_amdgcn_mfma_f32_16x16x32_bf16(AT[kt], bu, aT, 0, 0, 0);
                }
#pragma unroll
                for (int kt = 0; kt < 4; kt++) {
                    short8 bx = *(const short8*)(&xs[(nt * 16 + nr) * XS_LD + kt * 32 + quad * 8]);
                    aG = __builtin_amdgcn_mfma_f32_16x16x32_bf16(AG[kt], bx, aG, 0, 0, 0);
                }
                long node = row0 + nt * 16 + nr;
                if (node < NNODES) {
                    uint2 d;
                    d.x = pack2(sig_f(aG[0]) * sp_f(aT[0]), sig_f(aG[1]) * sp_f(aT[1]));
                    d.y = pack2(sig_f(aG[2]) * sp_f(aT[2]), sig_f(aG[3]) * sp_f(aT[3]));
                    *(uint2*)(M + node * HF + et * 16 + quad * 4) = d;
                }
            }
        }
    }
}

// ---------------- aggregation: x[v] += sp( sum_{e: tgt=v} M[src[e]] ) ----------------
__global__ __launch_bounds__(256) void agg_kernel(const u16* __restrict__ M,
                                                  const int* __restrict__ row_ptr,
                                                  const int* __restrict__ counts,
                                                  const int* __restrict__ es,
                                                  u16* __restrict__ x){
    int v = blockIdx.x * 4 + (threadIdx.x >> 6);
    int c = threadIdx.x & 63;                     // dword lane (2 bf16)
    if (v >= NNODES) return;
    int start = row_ptr[v], cnt = counts[v];
    float a0 = 0.f, a1 = 0.f;
    const unsigned* Mu = (const unsigned*)M;
    for (int e = 0; e < cnt; e++) {
        int s = es[start + e];
        unsigned u = Mu[s * 64 + c];
        a0 += bfu((u16)u);
        a1 += bfu((u16)(u >> 16));
    }
    unsigned* xu = (unsigned*)x;
    unsigned xv = xu[v * 64 + c];
    float x0 = bfu((u16)xv) + sp_f(a0);
    float x1 = bfu((u16)(xv >> 16)) + sp_f(a1);
    xu[v * 64 + c] = pack2(x0, x1);
}

// ---------------- head: per-graph sum (fused pool) + Wp/cnt + 2 FC + regression ----------------
__global__ __launch_bounds__(128) void head_kernel(const u16* __restrict__ x,
                                                   const int* __restrict__ gidx,
                                                   const void* __restrict__ ncnt,
                                                   const void* __restrict__ Wp,
                                                   const void* __restrict__ Wfc1, const void* __restrict__ bfc1,
                                                   const void* __restrict__ Wfc2, const void* __restrict__ bfc2,
                                                   const void* __restrict__ Wr,  const void* __restrict__ br,
                                                   void* __restrict__ out,
                                                   const int* __restrict__ flag){
    int g = blockIdx.x, t = threadIdx.x;
    bool f32 = *flag != 0;
    __shared__ float h0[HF], h1[HF];
    __shared__ float red[2];
    // node range of graph g (gidx sorted)
    int lo = 0, hi = NNODES;
    while (lo < hi) { int mid = (lo + hi) >> 1; if (gidx[mid] < g) lo = mid + 1; else hi = mid; }
    int start = lo;
    hi = NNODES;
    while (lo < hi) { int mid = (lo + hi) >> 1; if (gidx[mid] < g + 1) lo = mid + 1; else hi = mid; }
    int end = lo;
    float a = 0.f;
    for (int v = start; v < end; v++) a += bfu(x[(long)v * HF + t]);
    h0[t] = a;
    __syncthreads();
    float cnt = lf(ncnt, g, f32);
    a = 0.f;
    for (int k = 0; k < HF; k++) a += h0[k] * lf(Wp, k * HF + t, f32);
    h1[t] = sp_f(a / cnt);
    __syncthreads();
    a = lf(bfc1, t, f32);
    for (int k = 0; k < HF; k++) a += h1[k] * lf(Wfc1, k * HF + t, f32);
    float g2 = sp_f(a);
    __syncthreads();
    h0[t] = g2;
    __syncthreads();
    a = lf(bfc2, t, f32);
    for (int k = 0; k < HF; k++) a += h0[k] * lf(Wfc2, k * HF + t, f32);
    float g3 = sp_f(a);
    float p = g3 * lf(Wr, t, f32);
    for (int off = 32; off > 0; off >>= 1) p += __shfl_down(p, off, 64);
    if ((t & 63) == 0) red[t >> 6] = p;
    __syncthreads();
    if (t == 0) {
        float res = red[0] + red[1] + lf(br, 0, f32);
        if (f32) ((float*)out)[g] = res;
        else     ((u16*)out)[g]  = f2bf(res);
    }
}

extern "C" void kernel_launch(void* const* d_in, const int* in_sizes, int n_in,
                              void* d_out, int out_size, void* d_ws, size_t ws_size,
                              hipStream_t stream) {
    const int* nodes = (const int*)d_in[0];
    const int* esrc  = (const int*)d_in[1];
    const int* etgt  = (const int*)d_in[2];
    const int* gidx  = (const int*)d_in[3];

    size_t off = 0;
    char* w = (char*)d_ws;
    auto take = [&](size_t bytes) -> void* {
        void* p = w + off;
        off = (off + bytes + 255) & ~(size_t)255;
        return p;
    };

    int* flag    = (int*)take(256);
    u16* pwg     = (u16*)take((size_t)3 * HF * HF * 2);
    u16* pwe1    = (u16*)take((size_t)3 * HF * EF * 2);
    u16* pwe2    = (u16*)take((size_t)3 * EF * HF * 2);
    int* counts  = (int*)take((size_t)NNODES * 4);
    int* row_ptr = (int*)take((size_t)NNODES * 4);
    int* cursor  = (int*)take((size_t)NNODES * 4);
    int* es      = (int*)take((size_t)NEDGES * 4);
    int* bsums   = (int*)take(2048);
    int* boffs   = (int*)take(2048);
    u16* x       = (u16*)take((size_t)NNODES * HF * 2);
    u16* M       = (u16*)take((size_t)NNODES * HF * 2);

    detect_kernel<<<1, 256, 0, stream>>>((const u16*)d_in[5], flag);
    repack_all<<<(3 * 81920 + 255) / 256, 256, 0, stream>>>(d_in[6], d_in[7], d_in[8],
                                                            pwg, pwe1, pwe2, flag);
    embed_kernel<<<(NNODES * 64 + 255) / 256, 256, 0, stream>>>(nodes, d_in[5], x, flag);

    const int NB_SCAN = (NNODES + 255) / 256;
    const int NB_EDGE = (NEDGES + 255) / 256;
    hipMemsetAsync(counts, 0, (size_t)NNODES * 4, stream);
    count_kernel<<<NB_EDGE, 256, 0, stream>>>(etgt, counts);
    scan1_kernel<<<NB_SCAN, 256, 0, stream>>>(counts, row_ptr, bsums);
    scan2_kernel<<<1, 512, 0, stream>>>(bsums, boffs, NB_SCAN);
    scan3_kernel<<<NB_SCAN, 256, 0, stream>>>(row_ptr, boffs, cursor);
    fill_kernel<<<NB_EDGE, 256, 0, stream>>>(esrc, etgt, cursor, es);

    const int NBC = (NNODES + 63) / 64;   // 1563
    for (int c = 0; c < 3; c++) {
        conv_mfma<<<NBC, 256, 0, stream>>>(x,
            pwg  + (size_t)c * HF * HF,
            pwe1 + (size_t)c * HF * EF,
            pwe2 + (size_t)c * EF * HF, M);
        agg_kernel<<<(NNODES + 3) / 4, 256, 0, stream>>>(M, row_ptr, counts, es, x);
    }

    head_kernel<<<NGRAPHS, 128, 0, stream>>>(x, gidx, d_in[4], d_in[9],
                                             d_in[10], d_in[11], d_in[12], d_in[13],
                                             d_in[14], d_in[15], d_out, flag);
}

// Round 6
// 526.404 us; speedup vs baseline: 3.0937x; 1.1915x over previous
//
#include <hip/hip_runtime.h>
#include <hip/hip_bf16.h>

typedef unsigned short u16;
typedef __attribute__((ext_vector_type(8))) short short8;
typedef __attribute__((ext_vector_type(4))) float f32x4;

#define NNODES 100000
#define NEDGES 600000
#define NGRAPHS 512
#define HF 128
#define EF 256
#define XS_LD 136   // 128 + 8 pad (16B-aligned rows)
#define US_LD 264   // 256 + 8 pad

__device__ __forceinline__ float bfu(u16 u){ return __uint_as_float(((unsigned)u) << 16); }
__device__ __forceinline__ u16 f2bf(float f){
    unsigned u = __float_as_uint(f);
    unsigned r = (u + 0x7fff + ((u >> 16) & 1)) >> 16;
    return (u16)r;
}
__device__ __forceinline__ unsigned pack2(float a, float b){
    return (unsigned)f2bf(a) | ((unsigned)f2bf(b) << 16);
}

#if __has_builtin(__builtin_amdgcn_rcpf)
#define RCP1(x) __builtin_amdgcn_rcpf(x)
#else
#define RCP1(x) (1.f / (x))
#endif

// fast softplus / sigmoid via native v_exp/v_log/v_rcp (~1e-7 abs err)
__device__ __forceinline__ float sp_f(float x){
    return fmaxf(x, 0.f) + __logf(1.f + __expf(-fabsf(x)));
}
__device__ __forceinline__ float sig_f(float x){
    return RCP1(1.f + __expf(-x));
}
// flag-steered load of a "float" input that may be stored bf16 or fp32
__device__ __forceinline__ float lf(const void* p, long i, bool f32){
    return f32 ? ((const float*)p)[i] : bfu(((const u16*)p)[i]);
}

// in-register dtype detection: read 256 u16 of the embed table as bf16;
// true-bf16 N(0,0.05) weights never exceed 1.0, fp32-storage halves do ~50%.
__device__ __forceinline__ bool is_f32(const void* probe){
    const u16* p = (const u16*)probe;
    int lane = threadIdx.x & 63;
    int c = 0;
#pragma unroll
    for (int i = 0; i < 4; i++) c += (fabsf(bfu(p[lane * 4 + i])) > 1.0f) ? 1 : 0;
#pragma unroll
    for (int off = 32; off; off >>= 1) c += __shfl_xor(c, off, 64);
    return c > 8;
}

// ---------------- fused prep: weight repack + embedding + edge count ----------------
// blocks [0,960): repack conv weights -> MFMA fragment order (bf16)
//   P layout per [K][N] weight: [kt][nt][lane][8]; lane l holds
//   W[k = kt*32 + (l>>4)*8 + j][n = nt*16 + (l&15)], j=0..7.
// blocks [960,25960): embed  x[v][h] = emb[nodes[v]][h] (bf16 dword-packed)
// blocks [25960,28304): count edges per target (counts pre-zeroed by memset)
__global__ __launch_bounds__(256) void prep_kernel(const void* __restrict__ wg,
                                                   const void* __restrict__ we1,
                                                   const void* __restrict__ we2,
                                                   u16* __restrict__ pwg,
                                                   u16* __restrict__ pwe1,
                                                   u16* __restrict__ pwe2,
                                                   const int* __restrict__ nodes,
                                                   const void* __restrict__ emb,
                                                   u16* __restrict__ x,
                                                   const int* __restrict__ tgt,
                                                   int* __restrict__ counts){
    int b = blockIdx.x, t = threadIdx.x;
    if (b < 960) {
        bool f32 = is_f32(emb);
        int i = b * 256 + t;                       // < 3*81920
        int c = i / 81920, r = i % 81920;
        const void* src; u16* dst; int N, KN, l;
        if (r < 16384)      { src = wg;  dst = pwg;  N = HF; KN = 16384; l = r; }
        else if (r < 49152) { src = we1; dst = pwe1; N = EF; KN = 32768; l = r - 16384; }
        else                { src = we2; dst = pwe2; N = HF; KN = 32768; l = r - 49152; }
        int j = l & 7, lane = (l >> 3) & 63, rest = l >> 9;
        int NT = N >> 4, nt = rest % NT, kt = rest / NT;
        int k = kt * 32 + (lane >> 4) * 8 + j;
        int n = nt * 16 + (lane & 15);
        long base = (long)c * KN;
        dst[base + l] = f2bf(lf(src, base + (long)k * N + n, f32));
    } else if (b < 25960) {
        bool f32 = is_f32(emb);
        int i = (b - 960) * 256 + t;               // dword index, < NNODES*64 exactly
        int v = i >> 6, c = i & 63;
        long base = (long)nodes[v] * HF + c * 2;
        ((unsigned*)x)[i] = pack2(lf(emb, base, f32), lf(emb, base + 1, f32));
    } else {
        int e = (b - 25960) * 256 + t;
        if (e < NEDGES) atomicAdd(&counts[tgt[e]], 1);
    }
}

// ---------------- CSR build ----------------
__global__ __launch_bounds__(256) void scan1_kernel(const int* __restrict__ counts,
                                                    int* __restrict__ row_ptr,
                                                    int* __restrict__ bsums){
    __shared__ int s[256];
    int t = threadIdx.x;
    int i = blockIdx.x * 256 + t;
    int v = (i < NNODES) ? counts[i] : 0;
    s[t] = v; __syncthreads();
    for (int off = 1; off < 256; off <<= 1) {
        int a = (t >= off) ? s[t - off] : 0;
        __syncthreads();
        s[t] += a;
        __syncthreads();
    }
    if (i < NNODES) row_ptr[i] = s[t] - v;
    if (t == 255) bsums[blockIdx.x] = s[255];
}

__global__ __launch_bounds__(512) void scan2_kernel(const int* __restrict__ bsums,
                                                    int* __restrict__ boffs, int nb){
    __shared__ int s[512];
    int t = threadIdx.x;
    int v = (t < nb) ? bsums[t] : 0;
    s[t] = v; __syncthreads();
    for (int off = 1; off < 512; off <<= 1) {
        int a = (t >= off) ? s[t - off] : 0;
        __syncthreads();
        s[t] += a;
        __syncthreads();
    }
    if (t < nb) boffs[t] = s[t] - v;
}

__global__ __launch_bounds__(256) void scan3_kernel(int* __restrict__ row_ptr,
                                                    const int* __restrict__ boffs,
                                                    int* __restrict__ cursor){
    int i = blockIdx.x * 256 + threadIdx.x;
    if (i < NNODES) {
        int r = row_ptr[i] + boffs[blockIdx.x];
        row_ptr[i] = r;
        cursor[i]  = r;
    }
}

__global__ __launch_bounds__(256) void fill_kernel(const int* __restrict__ src,
                                                   const int* __restrict__ tgt,
                                                   int* __restrict__ cursor,
                                                   int* __restrict__ es){
    int e = blockIdx.x * 256 + threadIdx.x;
    if (e < NEDGES) {
        int pos = atomicAdd(&cursor[tgt[e]], 1);
        es[pos] = src[e];
    }
}

// ---------------- fused conv via transposed MFMA ----------------
// M = sig(x@Wg) * sp( sp(x@We1)@We2 ) for 64 nodes per block, 4 waves.
// Products computed transposed (features = M-dim, nodes = N-dim): C-layout
// gives each lane 4 consecutive features of one node -> b64 stores.
// Packed weights act as A-fragments of W^T (layout identity with B-of-W).
__global__ __launch_bounds__(256) void conv_mfma(const u16* __restrict__ x,
                                                 const u16* __restrict__ pwg,
                                                 const u16* __restrict__ pwe1,
                                                 const u16* __restrict__ pwe2,
                                                 u16* __restrict__ M){
    __shared__ u16 xs[64 * XS_LD];   // 17,408 B
    __shared__ u16 us[64 * US_LD];   // 33,792 B
    const int t = threadIdx.x;
    const int w = t >> 6, lane = t & 63;
    const int quad = lane >> 4, nr = lane & 15;
    const long row0 = (long)blockIdx.x * 64;

    // stage x tile (64 rows x 128 bf16), zero-pad past NNODES
    for (int c = t; c < 1024; c += 256) {
        int r = c >> 4, c8 = c & 15;
        long node = row0 + r;
        uint4 v = make_uint4(0u, 0u, 0u, 0u);
        if (node < NNODES) v = *(const uint4*)(x + node * HF + c8 * 8);
        *(uint4*)(&xs[r * XS_LD + c8 * 8]) = v;
    }
    __syncthreads();

    // ---- phase U: us[node][ef] = sp( (We1^T @ x^T)[ef][node] ) ----
    {
        short8 A[4][4];                            // [etl][kt]
#pragma unroll
        for (int etl = 0; etl < 4; etl++) {
            int et = w * 4 + etl;
#pragma unroll
            for (int kt = 0; kt < 4; kt++)
                A[etl][kt] = *(const short8*)(pwe1 + (((kt * 16 + et) * 64 + lane) << 3));
        }
#pragma unroll
        for (int nt = 0; nt < 4; nt++) {
            short8 bx[4];
#pragma unroll
            for (int kt = 0; kt < 4; kt++)
                bx[kt] = *(const short8*)(&xs[(nt * 16 + nr) * XS_LD + kt * 32 + quad * 8]);
#pragma unroll
            for (int etl = 0; etl < 4; etl++) {
                f32x4 acc = {0.f, 0.f, 0.f, 0.f};
#pragma unroll
                for (int kt = 0; kt < 4; kt++)
                    acc = __builtin_amdgcn_mfma_f32_16x16x32_bf16(A[etl][kt], bx[kt], acc, 0, 0, 0);
                uint2 d;
                d.x = pack2(sp_f(acc[0]), sp_f(acc[1]));
                d.y = pack2(sp_f(acc[2]), sp_f(acc[3]));
                *(uint2*)(&us[(nt * 16 + nr) * US_LD + (w * 4 + etl) * 16 + quad * 4]) = d;
            }
        }
    }
    __syncthreads();

    // ---- phase C: M[node][h] = sig((Wg^T@x^T)) * sp((We2^T@U^T)) ----
    {
#pragma unroll
        for (int c = 0; c < 2; c++) {
            int et = w * 2 + c;
            short8 AT[8], AG[4];
#pragma unroll
            for (int kt = 0; kt < 8; kt++)
                AT[kt] = *(const short8*)(pwe2 + (((kt * 8 + et) * 64 + lane) << 3));
#pragma unroll
            for (int kt = 0; kt < 4; kt++)
                AG[kt] = *(const short8*)(pwg + (((kt * 8 + et) * 64 + lane) << 3));
#pragma unroll
            for (int nt = 0; nt < 4; nt++) {
                f32x4 aT = {0.f, 0.f, 0.f, 0.f};
                f32x4 aG = {0.f, 0.f, 0.f, 0.f};
#pragma unroll
                for (int kt = 0; kt < 8; kt++) {
                    short8 bu = *(const short8*)(&us[(nt * 16 + nr) * US_LD + kt * 32 + quad * 8]);
                    aT = __builtin_amdgcn_mfma_f32_16x16x32_bf16(AT[kt], bu, aT, 0, 0, 0);
                }
#pragma unroll
                for (int kt = 0; kt < 4; kt++) {
                    short8 bx = *(const short8*)(&xs[(nt * 16 + nr) * XS_LD + kt * 32 + quad * 8]);
                    aG = __builtin_amdgcn_mfma_f32_16x16x32_bf16(AG[kt], bx, aG, 0, 0, 0);
                }
                long node = row0 + nt * 16 + nr;
                if (node < NNODES) {
                    uint2 d;
                    d.x = pack2(sig_f(aG[0]) * sp_f(aT[0]), sig_f(aG[1]) * sp_f(aT[1]));
                    d.y = pack2(sig_f(aG[2]) * sp_f(aT[2]), sig_f(aG[3]) * sp_f(aT[3]));
                    *(uint2*)(M + node * HF + et * 16 + quad * 4) = d;
                }
            }
        }
    }
}

// ---------------- aggregation: x[v] += sp( sum_{e: tgt=v} M[src[e]] ) ----------------
// uint2 per lane, 32 lanes per node row, 2 nodes per wave.
__global__ __launch_bounds__(256) void agg_kernel(const u16* __restrict__ M,
                                                  const int* __restrict__ row_ptr,
                                                  const int* __restrict__ counts,
                                                  const int* __restrict__ es,
                                                  u16* __restrict__ x){
    int wid = blockIdx.x * 4 + (threadIdx.x >> 6);
    int lane = threadIdx.x & 63;
    int half = lane >> 5, l = lane & 31;
    long v = (long)wid * 2 + half;
    if (v >= NNODES) return;
    int start = row_ptr[v], cnt = counts[v];
    float a0 = 0.f, a1 = 0.f, a2 = 0.f, a3 = 0.f;
    const uint2* Mu = (const uint2*)M;
    for (int e = 0; e < cnt; e++) {
        int s = es[start + e];
        uint2 u = Mu[(long)s * 32 + l];
        a0 += bfu((u16)u.x); a1 += bfu((u16)(u.x >> 16));
        a2 += bfu((u16)u.y); a3 += bfu((u16)(u.y >> 16));
    }
    uint2* xu = (uint2*)x;
    uint2 xv = xu[v * 32 + l];
    xv.x = pack2(bfu((u16)xv.x) + sp_f(a0), bfu((u16)(xv.x >> 16)) + sp_f(a1));
    xv.y = pack2(bfu((u16)xv.y) + sp_f(a2), bfu((u16)(xv.y >> 16)) + sp_f(a3));
    xu[v * 32 + l] = xv;
}

// ---------------- pooling: xsum[g] = sum of x rows of graph g (atomic flush) ----------------
// one wave = 64 consecutive nodes; gidx sorted -> wave-uniform boundary flush.
__global__ __launch_bounds__(256) void pool_kernel(const u16* __restrict__ x,
                                                   const int* __restrict__ gidx,
                                                   float* __restrict__ xsum){
    int wave = blockIdx.x * 4 + (threadIdx.x >> 6);
    int lane = threadIdx.x & 63;
    long base = (long)wave * 64;
    if (base >= NNODES) return;
    long end = base + 64; if (end > NNODES) end = NNODES;
    const unsigned* xu = (const unsigned*)x;
    int gcur = gidx[base];
    float a0 = 0.f, a1 = 0.f;
    for (long v = base; v < end; v++) {
        int g = gidx[v];                           // wave-uniform
        if (g != gcur) {
            atomicAdd(&xsum[gcur * HF + lane * 2 + 0], a0);
            atomicAdd(&xsum[gcur * HF + lane * 2 + 1], a1);
            a0 = a1 = 0.f; gcur = g;
        }
        unsigned u = xu[v * 64 + lane];
        a0 += bfu((u16)u);
        a1 += bfu((u16)(u >> 16));
    }
    atomicAdd(&xsum[gcur * HF + lane * 2 + 0], a0);
    atomicAdd(&xsum[gcur * HF + lane * 2 + 1], a1);
}

// ---------------- head: sp(xsum@Wp/cnt) -> 2x FC+sp -> regression ----------------
__global__ __launch_bounds__(128) void head_kernel(const float* __restrict__ xsum,
                                                   const void* __restrict__ ncnt,
                                                   const void* __restrict__ Wp,
                                                   const void* __restrict__ Wfc1, const void* __restrict__ bfc1,
                                                   const void* __restrict__ Wfc2, const void* __restrict__ bfc2,
                                                   const void* __restrict__ Wr,  const void* __restrict__ br,
                                                   void* __restrict__ out,
                                                   const void* __restrict__ probe){
    int g = blockIdx.x, t = threadIdx.x;
    bool f32 = is_f32(probe);
    __shared__ float h0[HF], h1[HF];
    __shared__ float red[2];
    h0[t] = xsum[g * HF + t];
    __syncthreads();
    float cnt = lf(ncnt, g, f32);
    float a = 0.f;
    for (int k = 0; k < HF; k++) a += h0[k] * lf(Wp, k * HF + t, f32);
    h1[t] = sp_f(a / cnt);
    __syncthreads();
    a = lf(bfc1, t, f32);
    for (int k = 0; k < HF; k++) a += h1[k] * lf(Wfc1, k * HF + t, f32);
    float g2 = sp_f(a);
    __syncthreads();
    h0[t] = g2;
    __syncthreads();
    a = lf(bfc2, t, f32);
    for (int k = 0; k < HF; k++) a += h0[k] * lf(Wfc2, k * HF + t, f32);
    float g3 = sp_f(a);
    float p = g3 * lf(Wr, t, f32);
    for (int off = 32; off > 0; off >>= 1) p += __shfl_down(p, off, 64);
    if ((t & 63) == 0) red[t >> 6] = p;
    __syncthreads();
    if (t == 0) {
        float res = red[0] + red[1] + lf(br, 0, f32);
        if (f32) ((float*)out)[g] = res;
        else     ((u16*)out)[g]  = f2bf(res);
    }
}

extern "C" void kernel_launch(void* const* d_in, const int* in_sizes, int n_in,
                              void* d_out, int out_size, void* d_ws, size_t ws_size,
                              hipStream_t stream) {
    const int* nodes = (const int*)d_in[0];
    const int* esrc  = (const int*)d_in[1];
    const int* etgt  = (const int*)d_in[2];
    const int* gidx  = (const int*)d_in[3];

    size_t off = 0;
    char* w = (char*)d_ws;
    auto take = [&](size_t bytes) -> void* {
        void* p = w + off;
        off = (off + bytes + 255) & ~(size_t)255;
        return p;
    };

    u16* pwg     = (u16*)take((size_t)3 * HF * HF * 2);
    u16* pwe1    = (u16*)take((size_t)3 * HF * EF * 2);
    u16* pwe2    = (u16*)take((size_t)3 * EF * HF * 2);
    int* counts  = (int*)take((size_t)NNODES * 4);
    int* row_ptr = (int*)take((size_t)NNODES * 4);
    int* cursor  = (int*)take((size_t)NNODES * 4);
    int* es      = (int*)take((size_t)NEDGES * 4);
    int* bsums   = (int*)take(2048);
    int* boffs   = (int*)take(2048);
    float* xsum  = (float*)take((size_t)NGRAPHS * HF * 4);
    u16* x       = (u16*)take((size_t)NNODES * HF * 2);
    u16* M       = (u16*)take((size_t)NNODES * HF * 2);

    hipMemsetAsync(counts, 0, (size_t)NNODES * 4, stream);
    hipMemsetAsync(xsum, 0, (size_t)NGRAPHS * HF * 4, stream);

    // prep: repack (960) + embed (25000) + count (2344)
    prep_kernel<<<28304, 256, 0, stream>>>(d_in[6], d_in[7], d_in[8], pwg, pwe1, pwe2,
                                           nodes, d_in[5], x, etgt, counts);

    const int NB_SCAN = (NNODES + 255) / 256;      // 391
    const int NB_EDGE = (NEDGES + 255) / 256;      // 2344
    scan1_kernel<<<NB_SCAN, 256, 0, stream>>>(counts, row_ptr, bsums);
    scan2_kernel<<<1, 512, 0, stream>>>(bsums, boffs, NB_SCAN);
    scan3_kernel<<<NB_SCAN, 256, 0, stream>>>(row_ptr, boffs, cursor);
    fill_kernel<<<NB_EDGE, 256, 0, stream>>>(esrc, etgt, cursor, es);

    const int NBC = (NNODES + 63) / 64;            // 1563
    for (int c = 0; c < 3; c++) {
        conv_mfma<<<NBC, 256, 0, stream>>>(x,
            pwg  + (size_t)c * HF * HF,
            pwe1 + (size_t)c * HF * EF,
            pwe2 + (size_t)c * EF * HF, M);
        agg_kernel<<<(NNODES + 7) / 8, 256, 0, stream>>>(M, row_ptr, counts, es, x);
    }

    pool_kernel<<<(NNODES + 255) / 256, 256, 0, stream>>>(x, gidx, xsum);
    head_kernel<<<NGRAPHS, 128, 0, stream>>>(xsum, d_in[4], d_in[9],
                                             d_in[10], d_in[11], d_in[12], d_in[13],
                                             d_in[14], d_in[15], d_out, d_in[5]);
}

// Round 7
// 452.304 us; speedup vs baseline: 3.6006x; 1.1638x over previous
//
#include <hip/hip_runtime.h>
#include <hip/hip_bf16.h>

typedef unsigned short u16;
typedef __attribute__((ext_vector_type(8))) short short8;
typedef __attribute__((ext_vector_type(4))) float f32x4;
typedef __attribute__((ext_vector_type(2))) __bf16 bf16x2;

#define NNODES 100000
#define NEDGES 600000
#define NGRAPHS 512
#define HF 128
#define EF 256
#define XS_LD 136   // 128 + 8 pad (16B-aligned rows)
#define US_LD 264   // 256 + 8 pad
#define GB 32       // graphs per head block

__device__ __forceinline__ float bfu(u16 u){ return __uint_as_float(((unsigned)u) << 16); }
__device__ __forceinline__ u16 f2bf(float f){
    unsigned u = __float_as_uint(f);
    unsigned r = (u + 0x7fff + ((u >> 16) & 1)) >> 16;
    return (u16)r;
}
// HW packed f32->bf16 RNE (v_cvt_pk_bf16_f32 on gfx950)
__device__ __forceinline__ unsigned pack2(float a, float b){
    bf16x2 v = { (__bf16)a, (__bf16)b };
    return __builtin_bit_cast(unsigned, v);
}

#if __has_builtin(__builtin_amdgcn_rcpf)
#define RCP1(x) __builtin_amdgcn_rcpf(x)
#else
#define RCP1(x) (1.f / (x))
#endif

// fast softplus / sigmoid via native v_exp/v_log/v_rcp (~1e-7 abs err)
__device__ __forceinline__ float sp_f(float x){
    return fmaxf(x, 0.f) + __logf(1.f + __expf(-fabsf(x)));
}
__device__ __forceinline__ float sig_f(float x){
    return RCP1(1.f + __expf(-x));
}
// flag-steered load of a "float" input that may be stored bf16 or fp32
__device__ __forceinline__ float lf(const void* p, long i, bool f32){
    return f32 ? ((const float*)p)[i] : bfu(((const u16*)p)[i]);
}

// in-register dtype detection: read 256 u16 of the embed table as bf16;
// true-bf16 N(0,0.05) weights never exceed 1.0, fp32-storage halves do ~50%.
__device__ __forceinline__ bool is_f32(const void* probe){
    const u16* p = (const u16*)probe;
    int lane = threadIdx.x & 63;
    int c = 0;
#pragma unroll
    for (int i = 0; i < 4; i++) c += (fabsf(bfu(p[lane * 4 + i])) > 1.0f) ? 1 : 0;
#pragma unroll
    for (int off = 32; off; off >>= 1) c += __shfl_xor(c, off, 64);
    return c > 8;
}

// ---------------- fused prep: weight repack + embedding + edge count ----------------
// P layout per [K][N] weight: [kt][nt][lane][8]; lane l holds
// W[k = kt*32 + (l>>4)*8 + j][n = nt*16 + (l&15)], j=0..7.
// blocks [0,960):      conv weights (Wg, We1, We2) x3 convs
// blocks [960,1152):   head weights (Wp, Wfc1, Wfc2)
// blocks [1152,26152): embed  x[v][h] = emb[nodes[v]][h]
// blocks [26152,28496): count edges per target (counts pre-zeroed)
__global__ __launch_bounds__(256) void prep_kernel(const void* __restrict__ wg,
                                                   const void* __restrict__ we1,
                                                   const void* __restrict__ we2,
                                                   const void* __restrict__ wp,
                                                   const void* __restrict__ wfc1,
                                                   const void* __restrict__ wfc2,
                                                   u16* __restrict__ pwg,
                                                   u16* __restrict__ pwe1,
                                                   u16* __restrict__ pwe2,
                                                   u16* __restrict__ pwp,
                                                   u16* __restrict__ pf1,
                                                   u16* __restrict__ pf2,
                                                   const int* __restrict__ nodes,
                                                   const void* __restrict__ emb,
                                                   u16* __restrict__ x,
                                                   const int* __restrict__ tgt,
                                                   int* __restrict__ counts){
    int b = blockIdx.x, t = threadIdx.x;
    if (b < 960) {
        bool f32 = is_f32(emb);
        int i = b * 256 + t;                       // < 3*81920
        int c = i / 81920, r = i % 81920;
        const void* src; u16* dst; int N, KN, l;
        if (r < 16384)      { src = wg;  dst = pwg;  N = HF; KN = 16384; l = r; }
        else if (r < 49152) { src = we1; dst = pwe1; N = EF; KN = 32768; l = r - 16384; }
        else                { src = we2; dst = pwe2; N = HF; KN = 32768; l = r - 49152; }
        int j = l & 7, lane = (l >> 3) & 63, rest = l >> 9;
        int NT = N >> 4, nt = rest % NT, kt = rest / NT;
        int k = kt * 32 + (lane >> 4) * 8 + j;
        int n = nt * 16 + (lane & 15);
        long base = (long)c * KN;
        dst[base + l] = f2bf(lf(src, base + (long)k * N + n, f32));
    } else if (b < 1152) {
        bool f32 = is_f32(emb);
        int i = (b - 960) * 256 + t;               // < 3*16384
        int c = i / 16384, l = i % 16384;
        const void* src = (c == 0) ? wp : (c == 1) ? wfc1 : wfc2;
        u16* dst = (c == 0) ? pwp : (c == 1) ? pf1 : pf2;
        int j = l & 7, lane = (l >> 3) & 63, rest = l >> 9;
        int nt = rest & 7, kt = rest >> 3;         // N=128 -> NT=8
        int k = kt * 32 + (lane >> 4) * 8 + j;
        int n = nt * 16 + (lane & 15);
        dst[l] = f2bf(lf(src, (long)k * HF + n, f32));
    } else if (b < 26152) {
        bool f32 = is_f32(emb);
        int i = (b - 1152) * 256 + t;              // dword index, < NNODES*64 exactly
        int v = i >> 6, c = i & 63;
        long base = (long)nodes[v] * HF + c * 2;
        ((unsigned*)x)[i] = pack2(lf(emb, base, f32), lf(emb, base + 1, f32));
    } else {
        int e = (b - 26152) * 256 + t;
        if (e < NEDGES) atomicAdd(&counts[tgt[e]], 1);
    }
}

// ---------------- CSR build ----------------
__global__ __launch_bounds__(256) void scan1_kernel(const int* __restrict__ counts,
                                                    int* __restrict__ row_ptr,
                                                    int* __restrict__ bsums){
    __shared__ int s[256];
    int t = threadIdx.x;
    int i = blockIdx.x * 256 + t;
    int v = (i < NNODES) ? counts[i] : 0;
    s[t] = v; __syncthreads();
    for (int off = 1; off < 256; off <<= 1) {
        int a = (t >= off) ? s[t - off] : 0;
        __syncthreads();
        s[t] += a;
        __syncthreads();
    }
    if (i < NNODES) row_ptr[i] = s[t] - v;
    if (t == 255) bsums[blockIdx.x] = s[255];
}

__global__ __launch_bounds__(512) void scan2_kernel(const int* __restrict__ bsums,
                                                    int* __restrict__ boffs, int nb){
    __shared__ int s[512];
    int t = threadIdx.x;
    int v = (t < nb) ? bsums[t] : 0;
    s[t] = v; __syncthreads();
    for (int off = 1; off < 512; off <<= 1) {
        int a = (t >= off) ? s[t - off] : 0;
        __syncthreads();
        s[t] += a;
        __syncthreads();
    }
    if (t < nb) boffs[t] = s[t] - v;
}

__global__ __launch_bounds__(256) void scan3_kernel(int* __restrict__ row_ptr,
                                                    const int* __restrict__ boffs,
                                                    int* __restrict__ cursor){
    int i = blockIdx.x * 256 + threadIdx.x;
    if (i < NNODES) {
        int r = row_ptr[i] + boffs[blockIdx.x];
        row_ptr[i] = r;
        cursor[i]  = r;
    }
}

__global__ __launch_bounds__(256) void fill_kernel(const int* __restrict__ src,
                                                   const int* __restrict__ tgt,
                                                   int* __restrict__ cursor,
                                                   int* __restrict__ es){
    int e = blockIdx.x * 256 + threadIdx.x;
    if (e < NEDGES) {
        int pos = atomicAdd(&cursor[tgt[e]], 1);
        es[pos] = src[e];
    }
}

// ---------------- fused conv via transposed MFMA ----------------
// M = sig(x@Wg) * sp( sp(x@We1)@We2 ) for 64 nodes per block, 4 waves.
__global__ __launch_bounds__(256) void conv_mfma(const u16* __restrict__ x,
                                                 const u16* __restrict__ pwg,
                                                 const u16* __restrict__ pwe1,
                                                 const u16* __restrict__ pwe2,
                                                 u16* __restrict__ M){
    __shared__ u16 xs[64 * XS_LD];   // 17,408 B
    __shared__ u16 us[64 * US_LD];   // 33,792 B
    const int t = threadIdx.x;
    const int w = t >> 6, lane = t & 63;
    const int quad = lane >> 4, nr = lane & 15;
    const long row0 = (long)blockIdx.x * 64;

    for (int c = t; c < 1024; c += 256) {
        int r = c >> 4, c8 = c & 15;
        long node = row0 + r;
        uint4 v = make_uint4(0u, 0u, 0u, 0u);
        if (node < NNODES) v = *(const uint4*)(x + node * HF + c8 * 8);
        *(uint4*)(&xs[r * XS_LD + c8 * 8]) = v;
    }
    __syncthreads();

    // ---- phase U: us[node][ef] = sp( (We1^T @ x^T)[ef][node] ) ----
    {
        short8 A[4][4];
#pragma unroll
        for (int etl = 0; etl < 4; etl++) {
            int et = w * 4 + etl;
#pragma unroll
            for (int kt = 0; kt < 4; kt++)
                A[etl][kt] = *(const short8*)(pwe1 + (((kt * 16 + et) * 64 + lane) << 3));
        }
#pragma unroll
        for (int nt = 0; nt < 4; nt++) {
            short8 bx[4];
#pragma unroll
            for (int kt = 0; kt < 4; kt++)
                bx[kt] = *(const short8*)(&xs[(nt * 16 + nr) * XS_LD + kt * 32 + quad * 8]);
#pragma unroll
            for (int etl = 0; etl < 4; etl++) {
                f32x4 acc = {0.f, 0.f, 0.f, 0.f};
#pragma unroll
                for (int kt = 0; kt < 4; kt++)
                    acc = __builtin_amdgcn_mfma_f32_16x16x32_bf16(A[etl][kt], bx[kt], acc, 0, 0, 0);
                uint2 d;
                d.x = pack2(sp_f(acc[0]), sp_f(acc[1]));
                d.y = pack2(sp_f(acc[2]), sp_f(acc[3]));
                *(uint2*)(&us[(nt * 16 + nr) * US_LD + (w * 4 + etl) * 16 + quad * 4]) = d;
            }
        }
    }
    __syncthreads();

    // ---- phase C: M[node][h] = sig((Wg^T@x^T)) * sp((We2^T@U^T)) ----
    {
#pragma unroll
        for (int c = 0; c < 2; c++) {
            int et = w * 2 + c;
            short8 AT[8], AG[4];
#pragma unroll
            for (int kt = 0; kt < 8; kt++)
                AT[kt] = *(const short8*)(pwe2 + (((kt * 8 + et) * 64 + lane) << 3));
#pragma unroll
            for (int kt = 0; kt < 4; kt++)
                AG[kt] = *(const short8*)(pwg + (((kt * 8 + et) * 64 + lane) << 3));
#pragma unroll
            for (int nt = 0; nt < 4; nt++) {
                f32x4 aT = {0.f, 0.f, 0.f, 0.f};
                f32x4 aG = {0.f, 0.f, 0.f, 0.f};
#pragma unroll
                for (int kt = 0; kt < 8; kt++) {
                    short8 bu = *(const short8*)(&us[(nt * 16 + nr) * US_LD + kt * 32 + quad * 8]);
                    aT = __builtin_amdgcn_mfma_f32_16x16x32_bf16(AT[kt], bu, aT, 0, 0, 0);
                }
#pragma unroll
                for (int kt = 0; kt < 4; kt++) {
                    short8 bx = *(const short8*)(&xs[(nt * 16 + nr) * XS_LD + kt * 32 + quad * 8]);
                    aG = __builtin_amdgcn_mfma_f32_16x16x32_bf16(AG[kt], bx, aG, 0, 0, 0);
                }
                long node = row0 + nt * 16 + nr;
                if (node < NNODES) {
                    uint2 d;
                    d.x = pack2(sig_f(aG[0]) * sp_f(aT[0]), sig_f(aG[1]) * sp_f(aT[1]));
                    d.y = pack2(sig_f(aG[2]) * sp_f(aT[2]), sig_f(aG[3]) * sp_f(aT[3]));
                    *(uint2*)(M + node * HF + et * 16 + quad * 4) = d;
                }
            }
        }
    }
}

// ---------------- aggregation: x[v] += sp( sum_{e: tgt=v} M[src[e]] ) ----------------
// uint4 per lane, 16 lanes per node row, 4 nodes per wave.
__global__ __launch_bounds__(256) void agg_kernel(const u16* __restrict__ M,
                                                  const int* __restrict__ row_ptr,
                                                  const int* __restrict__ counts,
                                                  const int* __restrict__ es,
                                                  u16* __restrict__ x){
    int wid = blockIdx.x * 4 + (threadIdx.x >> 6);
    int lane = threadIdx.x & 63;
    long v = (long)wid * 4 + (lane >> 4);
    int l = lane & 15;
    if (v >= NNODES) return;
    int start = row_ptr[v], cnt = counts[v];
    float a0 = 0.f, a1 = 0.f, a2 = 0.f, a3 = 0.f;
    float a4 = 0.f, a5 = 0.f, a6 = 0.f, a7 = 0.f;
    const uint4* Mu = (const uint4*)M;
    for (int e = 0; e < cnt; e++) {
        int s = es[start + e];
        uint4 u = Mu[(long)s * 16 + l];
        a0 += bfu((u16)u.x); a1 += bfu((u16)(u.x >> 16));
        a2 += bfu((u16)u.y); a3 += bfu((u16)(u.y >> 16));
        a4 += bfu((u16)u.z); a5 += bfu((u16)(u.z >> 16));
        a6 += bfu((u16)u.w); a7 += bfu((u16)(u.w >> 16));
    }
    uint4* xu = (uint4*)x;
    uint4 xv = xu[v * 16 + l];
    xv.x = pack2(bfu((u16)xv.x) + sp_f(a0), bfu((u16)(xv.x >> 16)) + sp_f(a1));
    xv.y = pack2(bfu((u16)xv.y) + sp_f(a2), bfu((u16)(xv.y >> 16)) + sp_f(a3));
    xv.z = pack2(bfu((u16)xv.z) + sp_f(a4), bfu((u16)(xv.z >> 16)) + sp_f(a5));
    xv.w = pack2(bfu((u16)xv.w) + sp_f(a6), bfu((u16)(xv.w >> 16)) + sp_f(a7));
    xu[v * 16 + l] = xv;
}

// ---------------- pooling: xsum[g] = sum of x rows of graph g (atomic flush) ----------------
__global__ __launch_bounds__(256) void pool_kernel(const u16* __restrict__ x,
                                                   const int* __restrict__ gidx,
                                                   float* __restrict__ xsum){
    int wave = blockIdx.x * 4 + (threadIdx.x >> 6);
    int lane = threadIdx.x & 63;
    long base = (long)wave * 64;
    if (base >= NNODES) return;
    long end = base + 64; if (end > NNODES) end = NNODES;
    const unsigned* xu = (const unsigned*)x;
    int gcur = gidx[base];
    float a0 = 0.f, a1 = 0.f;
    for (long v = base; v < end; v++) {
        int g = gidx[v];                           // wave-uniform
        if (g != gcur) {
            atomicAdd(&xsum[gcur * HF + lane * 2 + 0], a0);
            atomicAdd(&xsum[gcur * HF + lane * 2 + 1], a1);
            a0 = a1 = 0.f; gcur = g;
        }
        unsigned u = xu[v * 64 + lane];
        a0 += bfu((u16)u);
        a1 += bfu((u16)(u >> 16));
    }
    atomicAdd(&xsum[gcur * HF + lane * 2 + 0], a0);
    atomicAdd(&xsum[gcur * HF + lane * 2 + 1], a1);
}

// ---------------- head via transposed MFMA, bf16 hi+lo activations ----------------
// block = 32 graphs, 4 waves; all 3 FC layers block-local in LDS; 16 blocks.
__global__ __launch_bounds__(256) void head_mfma(const float* __restrict__ xsum,
                                                 const void* __restrict__ ncnt,
                                                 const u16* __restrict__ pwp,
                                                 const u16* __restrict__ pf1,
                                                 const u16* __restrict__ pf2,
                                                 const void* __restrict__ bfc1,
                                                 const void* __restrict__ bfc2,
                                                 const void* __restrict__ Wr,
                                                 const void* __restrict__ br,
                                                 void* __restrict__ out,
                                                 const void* __restrict__ probe){
    __shared__ u16 hibuf[2][GB][136];   // 17,408 B
    __shared__ u16 lobuf[2][GB][136];   // 17,408 B
    const int t = threadIdx.x;
    const int w = t >> 6, lane = t & 63;
    const int quad = lane >> 4, nr = lane & 15;
    const bool f32 = is_f32(probe);
    const int g0 = blockIdx.x * GB;

    // load xsum -> hi/lo bf16 (GB*64 dword pairs)
    for (int i = t; i < GB * 64; i += 256) {
        int g = i >> 6, c = (i & 63) * 2;
        float f0 = xsum[(g0 + g) * HF + c], f1 = xsum[(g0 + g) * HF + c + 1];
        u16 h0 = f2bf(f0), h1 = f2bf(f1);
        *(unsigned*)&hibuf[0][g][c] = (unsigned)h0 | ((unsigned)h1 << 16);
        *(unsigned*)&lobuf[0][g][c] = pack2(f0 - bfu(h0), f1 - bfu(h1));
    }
    __syncthreads();

    float rc[2];
#pragma unroll
    for (int nt = 0; nt < 2; nt++) rc[nt] = RCP1(lf(ncnt, g0 + nt * 16 + nr, f32));

    int cur = 0;
    for (int layer = 0; layer < 3; layer++) {
        const u16* pw = (layer == 0) ? pwp : (layer == 1) ? pf1 : pf2;
        const void* bias = (layer == 1) ? bfc1 : bfc2;
        int nxt = cur ^ 1;
#pragma unroll
        for (int c = 0; c < 2; c++) {
            int et = w * 2 + c;
            short8 A[4];
#pragma unroll
            for (int kt = 0; kt < 4; kt++)
                A[kt] = *(const short8*)(pw + (((kt * 8 + et) * 64 + lane) << 3));
#pragma unroll
            for (int nt = 0; nt < 2; nt++) {
                f32x4 acc = {0.f, 0.f, 0.f, 0.f};
#pragma unroll
                for (int kt = 0; kt < 4; kt++) {
                    short8 bh = *(const short8*)(&hibuf[cur][nt * 16 + nr][kt * 32 + quad * 8]);
                    short8 bl = *(const short8*)(&lobuf[cur][nt * 16 + nr][kt * 32 + quad * 8]);
                    acc = __builtin_amdgcn_mfma_f32_16x16x32_bf16(A[kt], bh, acc, 0, 0, 0);
                    acc = __builtin_amdgcn_mfma_f32_16x16x32_bf16(A[kt], bl, acc, 0, 0, 0);
                }
                int feat0 = et * 16 + quad * 4;
                float f[4];
#pragma unroll
                for (int r = 0; r < 4; r++) {
                    float a = (layer == 0) ? acc[r] * rc[nt]
                                           : acc[r] + lf(bias, feat0 + r, f32);
                    f[r] = sp_f(a);
                }
                u16 h[4]; float lo[4];
#pragma unroll
                for (int r = 0; r < 4; r++) { h[r] = f2bf(f[r]); lo[r] = f[r] - bfu(h[r]); }
                uint2 dh, dl;
                dh.x = (unsigned)h[0] | ((unsigned)h[1] << 16);
                dh.y = (unsigned)h[2] | ((unsigned)h[3] << 16);
                dl.x = pack2(lo[0], lo[1]);
                dl.y = pack2(lo[2], lo[3]);
                *(uint2*)&hibuf[nxt][nt * 16 + nr][feat0] = dh;
                *(uint2*)&lobuf[nxt][nt * 16 + nr][feat0] = dl;
            }
        }
        __syncthreads();
        cur = nxt;
    }

    // regression: out[g] = g3 . Wr + br ; 8 threads per graph
    int g = t >> 3, sub = t & 7;
    float p = 0.f;
    for (int k = sub * 16; k < sub * 16 + 16; k++) {
        float v = bfu(hibuf[cur][g][k]) + bfu(lobuf[cur][g][k]);
        p += v * lf(Wr, k, f32);
    }
    p += __shfl_down(p, 4, 64);
    p += __shfl_down(p, 2, 64);
    p += __shfl_down(p, 1, 64);
    if (sub == 0) {
        float res = p + lf(br, 0, f32);
        if (f32) ((float*)out)[g0 + g] = res;
        else     ((u16*)out)[g0 + g]  = f2bf(res);
    }
}

extern "C" void kernel_launch(void* const* d_in, const int* in_sizes, int n_in,
                              void* d_out, int out_size, void* d_ws, size_t ws_size,
                              hipStream_t stream) {
    const int* nodes = (const int*)d_in[0];
    const int* esrc  = (const int*)d_in[1];
    const int* etgt  = (const int*)d_in[2];
    const int* gidx  = (const int*)d_in[3];

    size_t off = 0;
    char* w = (char*)d_ws;
    auto take = [&](size_t bytes) -> void* {
        void* p = w + off;
        off = (off + bytes + 255) & ~(size_t)255;
        return p;
    };

    u16* pwg     = (u16*)take((size_t)3 * HF * HF * 2);
    u16* pwe1    = (u16*)take((size_t)3 * HF * EF * 2);
    u16* pwe2    = (u16*)take((size_t)3 * EF * HF * 2);
    u16* pwp     = (u16*)take((size_t)HF * HF * 2);
    u16* pf1     = (u16*)take((size_t)HF * HF * 2);
    u16* pf2     = (u16*)take((size_t)HF * HF * 2);
    int* counts  = (int*)take((size_t)NNODES * 4);
    int* row_ptr = (int*)take((size_t)NNODES * 4);
    int* cursor  = (int*)take((size_t)NNODES * 4);
    int* es      = (int*)take((size_t)NEDGES * 4);
    int* bsums   = (int*)take(2048);
    int* boffs   = (int*)take(2048);
    float* xsum  = (float*)take((size_t)NGRAPHS * HF * 4);
    u16* x       = (u16*)take((size_t)NNODES * HF * 2);
    u16* M       = (u16*)take((size_t)NNODES * HF * 2);

    hipMemsetAsync(counts, 0, (size_t)NNODES * 4, stream);
    hipMemsetAsync(xsum, 0, (size_t)NGRAPHS * HF * 4, stream);

    // prep: conv repack (960) + head repack (192) + embed (25000) + count (2344)
    prep_kernel<<<28496, 256, 0, stream>>>(d_in[6], d_in[7], d_in[8],
                                           d_in[9], d_in[10], d_in[12],
                                           pwg, pwe1, pwe2, pwp, pf1, pf2,
                                           nodes, d_in[5], x, etgt, counts);

    const int NB_SCAN = (NNODES + 255) / 256;      // 391
    const int NB_EDGE = (NEDGES + 255) / 256;      // 2344
    scan1_kernel<<<NB_SCAN, 256, 0, stream>>>(counts, row_ptr, bsums);
    scan2_kernel<<<1, 512, 0, stream>>>(bsums, boffs, NB_SCAN);
    scan3_kernel<<<NB_SCAN, 256, 0, stream>>>(row_ptr, boffs, cursor);
    fill_kernel<<<NB_EDGE, 256, 0, stream>>>(esrc, etgt, cursor, es);

    const int NBC = (NNODES + 63) / 64;            // 1563
    for (int c = 0; c < 3; c++) {
        conv_mfma<<<NBC, 256, 0, stream>>>(x,
            pwg  + (size_t)c * HF * HF,
            pwe1 + (size_t)c * HF * EF,
            pwe2 + (size_t)c * EF * HF, M);
        agg_kernel<<<(NNODES + 15) / 16, 256, 0, stream>>>(M, row_ptr, counts, es, x);
    }

    pool_kernel<<<(NNODES + 255) / 256, 256, 0, stream>>>(x, gidx, xsum);
    head_mfma<<<NGRAPHS / GB, 256, 0, stream>>>(xsum, d_in[4], pwp, pf1, pf2,
                                                d_in[11], d_in[13], d_in[14], d_in[15],
                                                d_out, d_in[5]);
}